// Round 2
// baseline (1114.652 us; speedup 1.0000x reference)
//
#include <hip/hip_runtime.h>
#include <hip/hip_bf16.h>

#define NN 100000
#define NE 1600000
#define DD 64
#define HH 128
#define NLAYERS 4
#define NGRAPH 64
#define NBUCKET 782   // ceil(NN/128)

// ---------------- CSR build ----------------

__global__ void k_count(const int* __restrict__ dst, int* __restrict__ cnt) {
  int e = blockIdx.x * 256 + threadIdx.x;
  atomicAdd(&cnt[dst[e]], 1);
}

__global__ void k_scan1(const int* __restrict__ cnt, int* __restrict__ offs,
                        int* __restrict__ bsum, int n) {
  __shared__ int s[256];
  int t = threadIdx.x;
  int i = blockIdx.x * 256 + t;
  int v = (i < n) ? cnt[i] : 0;
  s[t] = v;
  __syncthreads();
  for (int off = 1; off < 256; off <<= 1) {
    int x = (t >= off) ? s[t - off] : 0;
    __syncthreads();
    s[t] += x;
    __syncthreads();
  }
  if (i < n) offs[i] = s[t] - v;
  if (t == 255) bsum[blockIdx.x] = s[255];
}

__global__ void k_scan2(int* bsum, int nb) {
  __shared__ int s[512];
  int t = threadIdx.x;
  int v = (t < nb) ? bsum[t] : 0;
  s[t] = v;
  __syncthreads();
  for (int off = 1; off < 512; off <<= 1) {
    int x = (t >= off) ? s[t - off] : 0;
    __syncthreads();
    s[t] += x;
    __syncthreads();
  }
  if (t < nb) bsum[t] = s[t] - v;
}

// offs finalize + bucket cursor init (bucket = 128 consecutive dst nodes)
__global__ void k_scan3(int* __restrict__ offs, const int* __restrict__ bsum,
                        int* __restrict__ bcur, int n) {
  int i = blockIdx.x * 256 + threadIdx.x;
  if (i < n) {
    int o = offs[i] + bsum[i >> 8];
    offs[i] = o;
    if ((i & 127) == 0) bcur[i >> 7] = o;
  }
}

// pass A: scatter packed (dstLocal<<20 | src) into per-bucket contiguous regions
__global__ void k_fillA(const int* __restrict__ src, const int* __restrict__ dst,
                        int* __restrict__ bcur, unsigned int* __restrict__ tmp) {
  int e = blockIdx.x * 256 + threadIdx.x;
  int d = dst[e];
  int pos = atomicAdd(&bcur[d >> 7], 1);
  tmp[pos] = ((unsigned int)(d & 127) << 20) | (unsigned int)src[e];
}

// pass B: one block per bucket; LDS per-node cursors; scatter src into CSR slice
__global__ void k_fillB(const unsigned int* __restrict__ tmp,
                        const int* __restrict__ offs,
                        int* __restrict__ csr, int nedge) {
  __shared__ int lcur[128];
  int b = blockIdx.x;
  int t = threadIdx.x;
  int base = offs[b << 7];
  int end = (b == NBUCKET - 1) ? nedge : offs[(b + 1) << 7];
  if (t < 128) {
    int node = (b << 7) + t;
    lcur[t] = (node < NN) ? (offs[node] - base) : 0;
  }
  __syncthreads();
  for (int i = base + t; i < end; i += 256) {
    unsigned int v = tmp[i];
    int dl = v >> 20;
    int s = v & 0xFFFFF;
    int pos = atomicAdd(&lcur[dl], 1);
    csr[base + pos] = s;
  }
}

// ---------------- lin_in: h = x @ W_in + b_in ; rh = bf16(relu(h)) ----------------
__global__ void k_lin_in(const float* __restrict__ x, const float* __restrict__ W,
                         const float* __restrict__ b, float* __restrict__ h,
                         unsigned short* __restrict__ rh) {
  int t = threadIdx.x;
  int c = t & 63;
  int wv = blockIdx.x * 4 + (t >> 6);
  int n0 = wv * 4;
  float bc = b[c];
  float a0 = bc, a1 = bc, a2 = bc, a3 = bc;
  const float* x0 = x + n0 * 64;
#pragma unroll 8
  for (int k = 0; k < 64; k++) {
    float w = W[k * 64 + c];
    a0 += x0[k] * w;
    a1 += x0[64 + k] * w;
    a2 += x0[128 + k] * w;
    a3 += x0[192 + k] * w;
  }
  h[(n0 + 0) * 64 + c] = a0;
  h[(n0 + 1) * 64 + c] = a1;
  h[(n0 + 2) * 64 + c] = a2;
  h[(n0 + 3) * 64 + c] = a3;
  rh[(n0 + 0) * 64 + c] = __bfloat16_as_ushort(__float2bfloat16(fmaxf(a0, 0.f)));
  rh[(n0 + 1) * 64 + c] = __bfloat16_as_ushort(__float2bfloat16(fmaxf(a1, 0.f)));
  rh[(n0 + 2) * 64 + c] = __bfloat16_as_ushort(__float2bfloat16(fmaxf(a2, 0.f)));
  rh[(n0 + 3) * 64 + c] = __bfloat16_as_ushort(__float2bfloat16(fmaxf(a3, 0.f)));
}

// ---------------- aggregate: agg[i] = sum_{e: dst=i} rh[src] (bf16 in, bf16 out) ----
// 8 threads per node, each owns 8 bf16 (16B)
__global__ void k_agg(const unsigned short* __restrict__ rh,
                      const int* __restrict__ csr, const int* __restrict__ offs,
                      const int* __restrict__ cnt, unsigned short* __restrict__ agg) {
  int t = blockIdx.x * 256 + threadIdx.x;
  int node = t >> 3;
  int part = (t & 7) * 8;   // bf16 element offset
  int start = offs[node];
  int deg = cnt[node];
  float acc[8] = {0.f, 0.f, 0.f, 0.f, 0.f, 0.f, 0.f, 0.f};
  for (int j = 0; j < deg; j++) {
    int s = csr[start + j];
    uint4 v = *reinterpret_cast<const uint4*>(rh + (size_t)s * 64 + part);
    acc[0] += __uint_as_float(v.x << 16);
    acc[1] += __uint_as_float(v.x & 0xFFFF0000u);
    acc[2] += __uint_as_float(v.y << 16);
    acc[3] += __uint_as_float(v.y & 0xFFFF0000u);
    acc[4] += __uint_as_float(v.z << 16);
    acc[5] += __uint_as_float(v.z & 0xFFFF0000u);
    acc[6] += __uint_as_float(v.w << 16);
    acc[7] += __uint_as_float(v.w & 0xFFFF0000u);
  }
  ushort4 o0, o1;
  o0.x = __bfloat16_as_ushort(__float2bfloat16(acc[0]));
  o0.y = __bfloat16_as_ushort(__float2bfloat16(acc[1]));
  o0.z = __bfloat16_as_ushort(__float2bfloat16(acc[2]));
  o0.w = __bfloat16_as_ushort(__float2bfloat16(acc[3]));
  o1.x = __bfloat16_as_ushort(__float2bfloat16(acc[4]));
  o1.y = __bfloat16_as_ushort(__float2bfloat16(acc[5]));
  o1.z = __bfloat16_as_ushort(__float2bfloat16(acc[6]));
  o1.w = __bfloat16_as_ushort(__float2bfloat16(acc[7]));
  *reinterpret_cast<ushort4*>(agg + (size_t)node * 64 + part) = o0;
  *reinterpret_cast<ushort4*>(agg + (size_t)node * 64 + part + 4) = o1;
}

// ---------------- fused MLP per layer ----------------
__global__ __launch_bounds__(256) void k_mlp(
    float* __restrict__ h, const unsigned short* __restrict__ agg,
    const float* __restrict__ W1l, const float* __restrict__ b1l,
    const float* __restrict__ gl, const float* __restrict__ btl,
    const float* __restrict__ W2l, const float* __restrict__ b2l,
    const float* __restrict__ epsl, unsigned short* __restrict__ rh) {
  __shared__ __align__(16) float sW[8192];
  __shared__ __align__(16) float sZ[32 * 64];
  __shared__ __align__(16) float sR[32 * 128];
  __shared__ float sb1[128], sg[128], sbt[128], sb2[64];

  int t = threadIdx.x;
  int nbase = blockIdx.x * 32;

  for (int i = t; i < 2048; i += 256)
    ((float4*)sW)[i] = ((const float4*)W1l)[i];
  if (t < 128) { sb1[t] = b1l[t]; sg[t] = gl[t]; sbt[t] = btl[t]; }
  if (t < 64) sb2[t] = b2l[t];
  float epsv = 1.0f + *epsl;

  // z = (1+eps)*h + agg
  {
    const float4* hp = (const float4*)&h[(size_t)nbase * 64 + t * 8];
    uint4 av = ((const uint4*)agg)[(size_t)nbase * 8 + t];
    float4 h0 = hp[0], h1 = hp[1];
    float4 z0, z1;
    z0.x = epsv * h0.x + __uint_as_float(av.x << 16);
    z0.y = epsv * h0.y + __uint_as_float(av.x & 0xFFFF0000u);
    z0.z = epsv * h0.z + __uint_as_float(av.y << 16);
    z0.w = epsv * h0.w + __uint_as_float(av.y & 0xFFFF0000u);
    z1.x = epsv * h1.x + __uint_as_float(av.z << 16);
    z1.y = epsv * h1.y + __uint_as_float(av.z & 0xFFFF0000u);
    z1.z = epsv * h1.z + __uint_as_float(av.w << 16);
    z1.w = epsv * h1.w + __uint_as_float(av.w & 0xFFFF0000u);
    ((float4*)sZ)[t * 2] = z0;
    ((float4*)sZ)[t * 2 + 1] = z1;
  }
  __syncthreads();

  // phase B: r = relu(LN(z @ W1 + b1))
  int cg = t & 31;
  int ng = t >> 5;
  float acc[4][4];
#pragma unroll
  for (int i = 0; i < 4; i++)
#pragma unroll
    for (int j = 0; j < 4; j++) acc[i][j] = sb1[cg * 4 + j];

#pragma unroll 4
  for (int k = 0; k < 64; k++) {
    float4 w = ((float4*)sW)[k * 32 + cg];
#pragma unroll
    for (int i = 0; i < 4; i++) {
      float z = sZ[(ng * 4 + i) * 64 + k];
      acc[i][0] += z * w.x;
      acc[i][1] += z * w.y;
      acc[i][2] += z * w.z;
      acc[i][3] += z * w.w;
    }
  }

  float ps[4], pq[4];
#pragma unroll
  for (int i = 0; i < 4; i++) {
    ps[i] = acc[i][0] + acc[i][1] + acc[i][2] + acc[i][3];
    pq[i] = acc[i][0] * acc[i][0] + acc[i][1] * acc[i][1] +
            acc[i][2] * acc[i][2] + acc[i][3] * acc[i][3];
  }
#pragma unroll
  for (int m = 1; m <= 16; m <<= 1) {
#pragma unroll
    for (int i = 0; i < 4; i++) {
      ps[i] += __shfl_xor(ps[i], m);
      pq[i] += __shfl_xor(pq[i], m);
    }
  }
#pragma unroll
  for (int i = 0; i < 4; i++) {
    float mu = ps[i] * (1.0f / 128.0f);
    float var = pq[i] * (1.0f / 128.0f) - mu * mu;
    float rs = rsqrtf(var + 1e-5f);
    float4 r;
    float* rp = &r.x;
#pragma unroll
    for (int j = 0; j < 4; j++) {
      int c = cg * 4 + j;
      float v = (acc[i][j] - mu) * rs * sg[c] + sbt[c];
      rp[j] = fmaxf(v, 0.f);
    }
    ((float4*)sR)[((ng * 4 + i) * 128 + cg * 4) / 4] = r;
  }
  __syncthreads();

  for (int i = t; i < 2048; i += 256)
    ((float4*)sW)[i] = ((const float4*)W2l)[i];
  __syncthreads();

  // phase C: h += r @ W2 + b2 ; rh = bf16(relu(h_new))
  int cg2 = t & 15;
  int ng2 = t >> 4;
  int n0 = ng2 * 2, n1 = n0 + 1;
  float a0[4], a1[4];
#pragma unroll
  for (int j = 0; j < 4; j++) { a0[j] = sb2[cg2 * 4 + j]; a1[j] = a0[j]; }
#pragma unroll 4
  for (int k = 0; k < 128; k++) {
    float4 w = ((float4*)sW)[k * 16 + cg2];
    float r0 = sR[n0 * 128 + k];
    float r1 = sR[n1 * 128 + k];
    a0[0] += r0 * w.x; a0[1] += r0 * w.y; a0[2] += r0 * w.z; a0[3] += r0 * w.w;
    a1[0] += r1 * w.x; a1[1] += r1 * w.y; a1[2] += r1 * w.z; a1[3] += r1 * w.w;
  }
  {
    float4 h0 = *(const float4*)&h[(size_t)(nbase + n0) * 64 + cg2 * 4];
    float4 h1 = *(const float4*)&h[(size_t)(nbase + n1) * 64 + cg2 * 4];
    float4 o0, o1;
    o0.x = h0.x + a0[0]; o0.y = h0.y + a0[1]; o0.z = h0.z + a0[2]; o0.w = h0.w + a0[3];
    o1.x = h1.x + a1[0]; o1.y = h1.y + a1[1]; o1.z = h1.z + a1[2]; o1.w = h1.w + a1[3];
    *(float4*)&h[(size_t)(nbase + n0) * 64 + cg2 * 4] = o0;
    *(float4*)&h[(size_t)(nbase + n1) * 64 + cg2 * 4] = o1;
    ushort4 r0, r1;
    r0.x = __bfloat16_as_ushort(__float2bfloat16(fmaxf(o0.x, 0.f)));
    r0.y = __bfloat16_as_ushort(__float2bfloat16(fmaxf(o0.y, 0.f)));
    r0.z = __bfloat16_as_ushort(__float2bfloat16(fmaxf(o0.z, 0.f)));
    r0.w = __bfloat16_as_ushort(__float2bfloat16(fmaxf(o0.w, 0.f)));
    r1.x = __bfloat16_as_ushort(__float2bfloat16(fmaxf(o1.x, 0.f)));
    r1.y = __bfloat16_as_ushort(__float2bfloat16(fmaxf(o1.y, 0.f)));
    r1.z = __bfloat16_as_ushort(__float2bfloat16(fmaxf(o1.z, 0.f)));
    r1.w = __bfloat16_as_ushort(__float2bfloat16(fmaxf(o1.w, 0.f)));
    *(ushort4*)&rh[(size_t)(nbase + n0) * 64 + cg2 * 4] = r0;
    *(ushort4*)&rh[(size_t)(nbase + n1) * 64 + cg2 * 4] = r1;
  }
}

// ---------------- pooling ----------------
__global__ void k_pool(const float* __restrict__ h, const int* __restrict__ batch,
                       float* __restrict__ pooled, int n) {
  int t = threadIdx.x;
  int d = t & 63;
  int w = t >> 6;
  int n0 = blockIdx.x * 256 + w * 64;
  float acc = 0.f;
  int prev = -1;
  for (int i = 0; i < 64; i++) {
    int nn = n0 + i;
    if (nn >= n) break;
    int g = batch[nn];
    if (g != prev) {
      if (prev >= 0) atomicAdd(&pooled[prev * 64 + d], acc);
      prev = g;
      acc = 0.f;
    }
    acc += h[(size_t)nn * 64 + d];
  }
  if (prev >= 0) atomicAdd(&pooled[prev * 64 + d], acc);
}

// ---------------- output MLP ----------------
__global__ void k_out(const float* __restrict__ pooled, const float* __restrict__ Wo1,
                      const float* __restrict__ bo1, const float* __restrict__ Wo2,
                      const float* __restrict__ bo2, float* __restrict__ out) {
  __shared__ __align__(16) float sP[64 * 64];
  int t = threadIdx.x;
  for (int i = t; i < 1024; i += 256)
    ((float4*)sP)[i] = ((const float4*)pooled)[i];
  __syncthreads();
  int g = t >> 2;
  int q = t & 3;
  float acc = 0.f;
  for (int c = q * 32; c < q * 32 + 32; c++) {
    float t1 = bo1[c];
#pragma unroll 8
    for (int k = 0; k < 64; k++) t1 += sP[g * 64 + k] * Wo1[k * 128 + c];
    acc += fmaxf(t1, 0.f) * Wo2[c];
  }
  acc += __shfl_xor(acc, 1);
  acc += __shfl_xor(acc, 2);
  if (q == 0) out[g] = acc + bo2[0];
}

// ---------------- launch ----------------

static inline char* align_up(char* p, size_t a) {
  return (char*)(((uintptr_t)p + a - 1) & ~(uintptr_t)(a - 1));
}

extern "C" void kernel_launch(void* const* d_in, const int* in_sizes, int n_in,
                              void* d_out, int out_size, void* d_ws, size_t ws_size,
                              hipStream_t stream) {
  const float* x    = (const float*)d_in[0];
  const float* W_in = (const float*)d_in[1];
  const float* b_in = (const float*)d_in[2];
  const float* eps  = (const float*)d_in[3];
  const float* W1   = (const float*)d_in[4];
  const float* b1   = (const float*)d_in[5];
  const float* gam  = (const float*)d_in[6];
  const float* bet  = (const float*)d_in[7];
  const float* W2   = (const float*)d_in[8];
  const float* b2   = (const float*)d_in[9];
  const float* Wo1  = (const float*)d_in[10];
  const float* bo1  = (const float*)d_in[11];
  const float* Wo2  = (const float*)d_in[12];
  const float* bo2  = (const float*)d_in[13];
  const int* ei     = (const int*)d_in[14];
  const int* batch  = (const int*)d_in[15];
  float* out = (float*)d_out;

  const int* e_src = ei;
  const int* e_dst = ei + NE;

  char* p = (char*)d_ws;
  float* h = (float*)p;              p += (size_t)NN * 64 * 4;   // 25.6 MB
  unsigned short* agg = (unsigned short*)p;
  unsigned int* tmp = (unsigned int*)p;  // tmp aliases agg (disjoint in time)
                                     p += (size_t)NN * 64 * 2;   // 12.8 MB
  unsigned short* rh = (unsigned short*)p; p += (size_t)NN * 64 * 2; // 12.8 MB
  int* csr = (int*)p;                p += (size_t)NE * 4;        // 6.4 MB
  int* cnt = (int*)p;                p += (size_t)NN * 4;
  int* offs = (int*)p;               p += (size_t)NN * 4;
  int* bcur = (int*)p;               p += (size_t)1024 * 4;
  int* bsum = (int*)p;               p += 512 * 4;
  p = align_up(p, 256);
  float* pooled = (float*)p;         p += (size_t)NGRAPH * 64 * 4;

  const int SCAN_BLOCKS = (NN + 255) / 256;  // 391

  hipMemsetAsync(cnt, 0, (size_t)NN * 4, stream);
  hipMemsetAsync(pooled, 0, (size_t)NGRAPH * 64 * 4, stream);

  k_count<<<NE / 256, 256, 0, stream>>>(e_dst, cnt);
  k_scan1<<<SCAN_BLOCKS, 256, 0, stream>>>(cnt, offs, bsum, NN);
  k_scan2<<<1, 512, 0, stream>>>(bsum, SCAN_BLOCKS);
  k_scan3<<<SCAN_BLOCKS, 256, 0, stream>>>(offs, bsum, bcur, NN);
  k_fillA<<<NE / 256, 256, 0, stream>>>(e_src, e_dst, bcur, tmp);
  k_fillB<<<NBUCKET, 256, 0, stream>>>(tmp, offs, csr, NE);

  k_lin_in<<<NN / (4 * 4), 256, 0, stream>>>(x, W_in, b_in, h, rh);

  for (int l = 0; l < NLAYERS; l++) {
    k_agg<<<NN * 8 / 256, 256, 0, stream>>>(rh, csr, offs, cnt, agg);
    k_mlp<<<NN / 32, 256, 0, stream>>>(h, agg,
        W1 + (size_t)l * 64 * 128, b1 + (size_t)l * 128,
        gam + (size_t)l * 128, bet + (size_t)l * 128,
        W2 + (size_t)l * 128 * 64, b2 + (size_t)l * 64,
        eps + l, rh);
  }

  k_pool<<<SCAN_BLOCKS, 256, 0, stream>>>(h, batch, pooled, NN);
  k_out<<<1, 256, 0, stream>>>(pooled, Wo1, bo1, Wo2, bo2, out);
}

// Round 3
// 766.907 us; speedup vs baseline: 1.4534x; 1.4534x over previous
//
#include <hip/hip_runtime.h>
#include <hip/hip_bf16.h>

#define NN 100000
#define NE 1600000
#define DD 64
#define HH 128
#define NLAYERS 4
#define NGRAPH 64
#define NBUCKET 782        // ceil(NN/128) buckets of 128 dst nodes
#define NCHUNK 391         // ceil(NE/4096) edge chunks of 4096
#define NTOT (NBUCKET * NCHUNK)   // 305,762 (bucket-major histogram)

// ---------------- CSR build ----------------

__global__ void k_count(const int* __restrict__ dst, int* __restrict__ cnt) {
  int e = blockIdx.x * 256 + threadIdx.x;
  atomicAdd(&cnt[dst[e]], 1);
}

// generic per-256-block exclusive scan; safe for out==in
__global__ void k_scan1(const int* __restrict__ in, int* __restrict__ out,
                        int* __restrict__ bsum, int n) {
  __shared__ int s[256];
  int t = threadIdx.x;
  int i = blockIdx.x * 256 + t;
  int v = (i < n) ? in[i] : 0;
  s[t] = v;
  __syncthreads();
  for (int off = 1; off < 256; off <<= 1) {
    int x = (t >= off) ? s[t - off] : 0;
    __syncthreads();
    s[t] += x;
    __syncthreads();
  }
  if (i < n) out[i] = s[t] - v;
  if (t == 255) bsum[blockIdx.x] = s[255];
}

// exclusive scan of up to 512 block sums (node-level scan)
__global__ void k_scan2(int* bsum, int nb) {
  __shared__ int s[512];
  int t = threadIdx.x;
  int v = (t < nb) ? bsum[t] : 0;
  s[t] = v;
  __syncthreads();
  for (int off = 1; off < 512; off <<= 1) {
    int x = (t >= off) ? s[t - off] : 0;
    __syncthreads();
    s[t] += x;
    __syncthreads();
  }
  if (t < nb) bsum[t] = s[t] - v;
}

// exclusive scan of up to 1280 block sums (histogram-level scan), in place
__global__ void k_scan2b(int* bsum, int nb) {
  __shared__ int s[256];
  int t = threadIdx.x;
  int base = t * 5;
  int v[5];
  int sum = 0;
#pragma unroll
  for (int j = 0; j < 5; j++) {
    int i = base + j;
    v[j] = (i < nb) ? bsum[i] : 0;
    sum += v[j];
  }
  s[t] = sum;
  __syncthreads();
  for (int off = 1; off < 256; off <<= 1) {
    int x = (t >= off) ? s[t - off] : 0;
    __syncthreads();
    s[t] += x;
    __syncthreads();
  }
  int ex = s[t] - sum;
#pragma unroll
  for (int j = 0; j < 5; j++) {
    int i = base + j;
    if (i < nb) { int vv = v[j]; bsum[i] = ex; ex += vv; }
  }
}

// finalize node offsets
__global__ void k_scan3(int* __restrict__ offs, const int* __restrict__ bsum, int n) {
  int i = blockIdx.x * 256 + threadIdx.x;
  if (i < n) offs[i] += bsum[i >> 8];
}

// per-chunk LDS histogram over buckets -> hist[bucket * NCHUNK + chunk]
__global__ void k_hist(const int* __restrict__ dst, int* __restrict__ hist) {
  __shared__ int lh[NBUCKET];
  int t = threadIdx.x;
  int blk = blockIdx.x;
  for (int i = t; i < NBUCKET; i += 256) lh[i] = 0;
  __syncthreads();
  int cb = blk * 4096;
  int end = min(cb + 4096, NE);
  for (int i = cb + t; i < end; i += 256)
    atomicAdd(&lh[dst[i] >> 7], 1);
  __syncthreads();
  for (int i = t; i < NBUCKET; i += 256)
    hist[i * NCHUNK + blk] = lh[i];
}

// atomic-free scatter: positions reserved by the scanned histogram
__global__ void k_scatter(const int* __restrict__ src, const int* __restrict__ dst,
                          const int* __restrict__ hist, unsigned int* __restrict__ tmp) {
  __shared__ int lcur[NBUCKET];
  int t = threadIdx.x;
  int blk = blockIdx.x;
  for (int i = t; i < NBUCKET; i += 256) lcur[i] = hist[i * NCHUNK + blk];
  __syncthreads();
  int cb = blk * 4096;
  int end = min(cb + 4096, NE);
  for (int i = cb + t; i < end; i += 256) {
    int d = dst[i];
    int pos = atomicAdd(&lcur[d >> 7], 1);   // LDS atomic, ~5 ops/bucket/block
    tmp[pos] = ((unsigned int)(d & 127) << 20) | (unsigned int)src[i];
  }
}

// per-bucket: LDS per-node cursors; scatter src into per-node CSR slices
__global__ void k_fillB(const unsigned int* __restrict__ tmp,
                        const int* __restrict__ offs,
                        int* __restrict__ csr, int nedge) {
  __shared__ int lcur[128];
  int b = blockIdx.x;
  int t = threadIdx.x;
  int base = offs[b << 7];
  int end = (b == NBUCKET - 1) ? nedge : offs[(b + 1) << 7];
  if (t < 128) {
    int node = (b << 7) + t;
    lcur[t] = (node < NN) ? (offs[node] - base) : 0;
  }
  __syncthreads();
  for (int i = base + t; i < end; i += 256) {
    unsigned int v = tmp[i];
    int dl = v >> 20;
    int s = v & 0xFFFFF;
    int pos = atomicAdd(&lcur[dl], 1);
    csr[base + pos] = s;
  }
}

// ---------------- lin_in: h = x @ W_in + b_in ; rh = bf16(relu(h)) ----------------
__global__ void k_lin_in(const float* __restrict__ x, const float* __restrict__ W,
                         const float* __restrict__ b, float* __restrict__ h,
                         unsigned short* __restrict__ rh) {
  int t = threadIdx.x;
  int c = t & 63;
  int wv = blockIdx.x * 4 + (t >> 6);
  int n0 = wv * 4;
  float bc = b[c];
  float a0 = bc, a1 = bc, a2 = bc, a3 = bc;
  const float* x0 = x + n0 * 64;
#pragma unroll 8
  for (int k = 0; k < 64; k++) {
    float w = W[k * 64 + c];
    a0 += x0[k] * w;
    a1 += x0[64 + k] * w;
    a2 += x0[128 + k] * w;
    a3 += x0[192 + k] * w;
  }
  h[(n0 + 0) * 64 + c] = a0;
  h[(n0 + 1) * 64 + c] = a1;
  h[(n0 + 2) * 64 + c] = a2;
  h[(n0 + 3) * 64 + c] = a3;
  rh[(n0 + 0) * 64 + c] = __bfloat16_as_ushort(__float2bfloat16(fmaxf(a0, 0.f)));
  rh[(n0 + 1) * 64 + c] = __bfloat16_as_ushort(__float2bfloat16(fmaxf(a1, 0.f)));
  rh[(n0 + 2) * 64 + c] = __bfloat16_as_ushort(__float2bfloat16(fmaxf(a2, 0.f)));
  rh[(n0 + 3) * 64 + c] = __bfloat16_as_ushort(__float2bfloat16(fmaxf(a3, 0.f)));
}

// ---------------- aggregate: agg[i] = sum_{e: dst=i} rh[src] (bf16 in/out) ----------
__global__ void k_agg(const unsigned short* __restrict__ rh,
                      const int* __restrict__ csr, const int* __restrict__ offs,
                      const int* __restrict__ cnt, unsigned short* __restrict__ agg) {
  int t = blockIdx.x * 256 + threadIdx.x;
  int node = t >> 3;
  int part = (t & 7) * 8;
  int start = offs[node];
  int deg = cnt[node];
  float acc[8] = {0.f, 0.f, 0.f, 0.f, 0.f, 0.f, 0.f, 0.f};
  for (int j = 0; j < deg; j++) {
    int s = csr[start + j];
    uint4 v = *reinterpret_cast<const uint4*>(rh + (size_t)s * 64 + part);
    acc[0] += __uint_as_float(v.x << 16);
    acc[1] += __uint_as_float(v.x & 0xFFFF0000u);
    acc[2] += __uint_as_float(v.y << 16);
    acc[3] += __uint_as_float(v.y & 0xFFFF0000u);
    acc[4] += __uint_as_float(v.z << 16);
    acc[5] += __uint_as_float(v.z & 0xFFFF0000u);
    acc[6] += __uint_as_float(v.w << 16);
    acc[7] += __uint_as_float(v.w & 0xFFFF0000u);
  }
  ushort4 o0, o1;
  o0.x = __bfloat16_as_ushort(__float2bfloat16(acc[0]));
  o0.y = __bfloat16_as_ushort(__float2bfloat16(acc[1]));
  o0.z = __bfloat16_as_ushort(__float2bfloat16(acc[2]));
  o0.w = __bfloat16_as_ushort(__float2bfloat16(acc[3]));
  o1.x = __bfloat16_as_ushort(__float2bfloat16(acc[4]));
  o1.y = __bfloat16_as_ushort(__float2bfloat16(acc[5]));
  o1.z = __bfloat16_as_ushort(__float2bfloat16(acc[6]));
  o1.w = __bfloat16_as_ushort(__float2bfloat16(acc[7]));
  *reinterpret_cast<ushort4*>(agg + (size_t)node * 64 + part) = o0;
  *reinterpret_cast<ushort4*>(agg + (size_t)node * 64 + part + 4) = o1;
}

// ---------------- fused MLP per layer ----------------
__global__ __launch_bounds__(256) void k_mlp(
    float* __restrict__ h, const unsigned short* __restrict__ agg,
    const float* __restrict__ W1l, const float* __restrict__ b1l,
    const float* __restrict__ gl, const float* __restrict__ btl,
    const float* __restrict__ W2l, const float* __restrict__ b2l,
    const float* __restrict__ epsl, unsigned short* __restrict__ rh) {
  __shared__ __align__(16) float sW[8192];
  __shared__ __align__(16) float sZ[32 * 64];
  __shared__ __align__(16) float sR[32 * 128];
  __shared__ float sb1[128], sg[128], sbt[128], sb2[64];

  int t = threadIdx.x;
  int nbase = blockIdx.x * 32;

  for (int i = t; i < 2048; i += 256)
    ((float4*)sW)[i] = ((const float4*)W1l)[i];
  if (t < 128) { sb1[t] = b1l[t]; sg[t] = gl[t]; sbt[t] = btl[t]; }
  if (t < 64) sb2[t] = b2l[t];
  float epsv = 1.0f + *epsl;

  {
    const float4* hp = (const float4*)&h[(size_t)nbase * 64 + t * 8];
    uint4 av = ((const uint4*)agg)[(size_t)nbase * 8 + t];
    float4 h0 = hp[0], h1 = hp[1];
    float4 z0, z1;
    z0.x = epsv * h0.x + __uint_as_float(av.x << 16);
    z0.y = epsv * h0.y + __uint_as_float(av.x & 0xFFFF0000u);
    z0.z = epsv * h0.z + __uint_as_float(av.y << 16);
    z0.w = epsv * h0.w + __uint_as_float(av.y & 0xFFFF0000u);
    z1.x = epsv * h1.x + __uint_as_float(av.z << 16);
    z1.y = epsv * h1.y + __uint_as_float(av.z & 0xFFFF0000u);
    z1.z = epsv * h1.z + __uint_as_float(av.w << 16);
    z1.w = epsv * h1.w + __uint_as_float(av.w & 0xFFFF0000u);
    ((float4*)sZ)[t * 2] = z0;
    ((float4*)sZ)[t * 2 + 1] = z1;
  }
  __syncthreads();

  int cg = t & 31;
  int ng = t >> 5;
  float acc[4][4];
#pragma unroll
  for (int i = 0; i < 4; i++)
#pragma unroll
    for (int j = 0; j < 4; j++) acc[i][j] = sb1[cg * 4 + j];

#pragma unroll 4
  for (int k = 0; k < 64; k++) {
    float4 w = ((float4*)sW)[k * 32 + cg];
#pragma unroll
    for (int i = 0; i < 4; i++) {
      float z = sZ[(ng * 4 + i) * 64 + k];
      acc[i][0] += z * w.x;
      acc[i][1] += z * w.y;
      acc[i][2] += z * w.z;
      acc[i][3] += z * w.w;
    }
  }

  float ps[4], pq[4];
#pragma unroll
  for (int i = 0; i < 4; i++) {
    ps[i] = acc[i][0] + acc[i][1] + acc[i][2] + acc[i][3];
    pq[i] = acc[i][0] * acc[i][0] + acc[i][1] * acc[i][1] +
            acc[i][2] * acc[i][2] + acc[i][3] * acc[i][3];
  }
#pragma unroll
  for (int m = 1; m <= 16; m <<= 1) {
#pragma unroll
    for (int i = 0; i < 4; i++) {
      ps[i] += __shfl_xor(ps[i], m);
      pq[i] += __shfl_xor(pq[i], m);
    }
  }
#pragma unroll
  for (int i = 0; i < 4; i++) {
    float mu = ps[i] * (1.0f / 128.0f);
    float var = pq[i] * (1.0f / 128.0f) - mu * mu;
    float rs = rsqrtf(var + 1e-5f);
    float4 r;
    float* rp = &r.x;
#pragma unroll
    for (int j = 0; j < 4; j++) {
      int c = cg * 4 + j;
      float v = (acc[i][j] - mu) * rs * sg[c] + sbt[c];
      rp[j] = fmaxf(v, 0.f);
    }
    ((float4*)sR)[((ng * 4 + i) * 128 + cg * 4) / 4] = r;
  }
  __syncthreads();

  for (int i = t; i < 2048; i += 256)
    ((float4*)sW)[i] = ((const float4*)W2l)[i];
  __syncthreads();

  int cg2 = t & 15;
  int ng2 = t >> 4;
  int n0 = ng2 * 2, n1 = n0 + 1;
  float a0[4], a1[4];
#pragma unroll
  for (int j = 0; j < 4; j++) { a0[j] = sb2[cg2 * 4 + j]; a1[j] = a0[j]; }
#pragma unroll 4
  for (int k = 0; k < 128; k++) {
    float4 w = ((float4*)sW)[k * 16 + cg2];
    float r0 = sR[n0 * 128 + k];
    float r1 = sR[n1 * 128 + k];
    a0[0] += r0 * w.x; a0[1] += r0 * w.y; a0[2] += r0 * w.z; a0[3] += r0 * w.w;
    a1[0] += r1 * w.x; a1[1] += r1 * w.y; a1[2] += r1 * w.z; a1[3] += r1 * w.w;
  }
  {
    float4 h0 = *(const float4*)&h[(size_t)(nbase + n0) * 64 + cg2 * 4];
    float4 h1 = *(const float4*)&h[(size_t)(nbase + n1) * 64 + cg2 * 4];
    float4 o0, o1;
    o0.x = h0.x + a0[0]; o0.y = h0.y + a0[1]; o0.z = h0.z + a0[2]; o0.w = h0.w + a0[3];
    o1.x = h1.x + a1[0]; o1.y = h1.y + a1[1]; o1.z = h1.z + a1[2]; o1.w = h1.w + a1[3];
    *(float4*)&h[(size_t)(nbase + n0) * 64 + cg2 * 4] = o0;
    *(float4*)&h[(size_t)(nbase + n1) * 64 + cg2 * 4] = o1;
    ushort4 r0, r1;
    r0.x = __bfloat16_as_ushort(__float2bfloat16(fmaxf(o0.x, 0.f)));
    r0.y = __bfloat16_as_ushort(__float2bfloat16(fmaxf(o0.y, 0.f)));
    r0.z = __bfloat16_as_ushort(__float2bfloat16(fmaxf(o0.z, 0.f)));
    r0.w = __bfloat16_as_ushort(__float2bfloat16(fmaxf(o0.w, 0.f)));
    r1.x = __bfloat16_as_ushort(__float2bfloat16(fmaxf(o1.x, 0.f)));
    r1.y = __bfloat16_as_ushort(__float2bfloat16(fmaxf(o1.y, 0.f)));
    r1.z = __bfloat16_as_ushort(__float2bfloat16(fmaxf(o1.z, 0.f)));
    r1.w = __bfloat16_as_ushort(__float2bfloat16(fmaxf(o1.w, 0.f)));
    *(ushort4*)&rh[(size_t)(nbase + n0) * 64 + cg2 * 4] = r0;
    *(ushort4*)&rh[(size_t)(nbase + n1) * 64 + cg2 * 4] = r1;
  }
}

// ---------------- pooling ----------------
__global__ void k_pool(const float* __restrict__ h, const int* __restrict__ batch,
                       float* __restrict__ pooled, int n) {
  int t = threadIdx.x;
  int d = t & 63;
  int w = t >> 6;
  int n0 = blockIdx.x * 256 + w * 64;
  float acc = 0.f;
  int prev = -1;
  for (int i = 0; i < 64; i++) {
    int nn = n0 + i;
    if (nn >= n) break;
    int g = batch[nn];
    if (g != prev) {
      if (prev >= 0) atomicAdd(&pooled[prev * 64 + d], acc);
      prev = g;
      acc = 0.f;
    }
    acc += h[(size_t)nn * 64 + d];
  }
  if (prev >= 0) atomicAdd(&pooled[prev * 64 + d], acc);
}

// ---------------- output MLP ----------------
__global__ void k_out(const float* __restrict__ pooled, const float* __restrict__ Wo1,
                      const float* __restrict__ bo1, const float* __restrict__ Wo2,
                      const float* __restrict__ bo2, float* __restrict__ out) {
  __shared__ __align__(16) float sP[64 * 64];
  int t = threadIdx.x;
  for (int i = t; i < 1024; i += 256)
    ((float4*)sP)[i] = ((const float4*)pooled)[i];
  __syncthreads();
  int g = t >> 2;
  int q = t & 3;
  float acc = 0.f;
  for (int c = q * 32; c < q * 32 + 32; c++) {
    float t1 = bo1[c];
#pragma unroll 8
    for (int k = 0; k < 64; k++) t1 += sP[g * 64 + k] * Wo1[k * 128 + c];
    acc += fmaxf(t1, 0.f) * Wo2[c];
  }
  acc += __shfl_xor(acc, 1);
  acc += __shfl_xor(acc, 2);
  if (q == 0) out[g] = acc + bo2[0];
}

// ---------------- launch ----------------

static inline char* align_up(char* p, size_t a) {
  return (char*)(((uintptr_t)p + a - 1) & ~(uintptr_t)(a - 1));
}

extern "C" void kernel_launch(void* const* d_in, const int* in_sizes, int n_in,
                              void* d_out, int out_size, void* d_ws, size_t ws_size,
                              hipStream_t stream) {
  const float* x    = (const float*)d_in[0];
  const float* W_in = (const float*)d_in[1];
  const float* b_in = (const float*)d_in[2];
  const float* eps  = (const float*)d_in[3];
  const float* W1   = (const float*)d_in[4];
  const float* b1   = (const float*)d_in[5];
  const float* gam  = (const float*)d_in[6];
  const float* bet  = (const float*)d_in[7];
  const float* W2   = (const float*)d_in[8];
  const float* b2   = (const float*)d_in[9];
  const float* Wo1  = (const float*)d_in[10];
  const float* bo1  = (const float*)d_in[11];
  const float* Wo2  = (const float*)d_in[12];
  const float* bo2  = (const float*)d_in[13];
  const int* ei     = (const int*)d_in[14];
  const int* batch  = (const int*)d_in[15];
  float* out = (float*)d_out;

  const int* e_src = ei;
  const int* e_dst = ei + NE;

  char* p = (char*)d_ws;
  float* h = (float*)p;              p += (size_t)NN * 64 * 4;     // 25.6 MB
  unsigned short* agg = (unsigned short*)p;
  unsigned int* tmp = (unsigned int*)p;   // tmp aliases agg (disjoint in time)
                                     p += (size_t)NN * 64 * 2;     // 12.8 MB
  unsigned short* rh = (unsigned short*)p; p += (size_t)NN * 64 * 2; // 12.8 MB
  int* csr = (int*)p;
  int* hist = (int*)p;               // hist aliases csr (hist dead before fillB writes csr)
                                     p += (size_t)NE * 4;          // 6.4 MB
  int* cnt = (int*)p;                p += (size_t)NN * 4;
  int* offs = (int*)p;               p += (size_t)NN * 4;
  int* bsum = (int*)p;               p += 512 * 4;
  int* bsumH = (int*)p;              p += 1280 * 4;
  p = align_up(p, 256);
  float* pooled = (float*)p;         p += (size_t)NGRAPH * 64 * 4;

  const int SCAN_BLOCKS = (NN + 255) / 256;          // 391
  const int SCAN_BLOCKS_H = (NTOT + 255) / 256;      // 1195

  hipMemsetAsync(cnt, 0, (size_t)NN * 4, stream);
  hipMemsetAsync(pooled, 0, (size_t)NGRAPH * 64 * 4, stream);

  // node-level degree + offsets
  k_count<<<NE / 256, 256, 0, stream>>>(e_dst, cnt);
  k_scan1<<<SCAN_BLOCKS, 256, 0, stream>>>(cnt, offs, bsum, NN);
  k_scan2<<<1, 512, 0, stream>>>(bsum, SCAN_BLOCKS);
  k_scan3<<<SCAN_BLOCKS, 256, 0, stream>>>(offs, bsum, NN);

  // bucket-level counting sort (atomic-free reservation)
  k_hist<<<NCHUNK, 256, 0, stream>>>(e_dst, hist);
  k_scan1<<<SCAN_BLOCKS_H, 256, 0, stream>>>(hist, hist, bsumH, NTOT);
  k_scan2b<<<1, 256, 0, stream>>>(bsumH, SCAN_BLOCKS_H);
  k_scan3<<<SCAN_BLOCKS_H, 256, 0, stream>>>(hist, bsumH, NTOT);
  k_scatter<<<NCHUNK, 256, 0, stream>>>(e_src, e_dst, hist, tmp);
  k_fillB<<<NBUCKET, 256, 0, stream>>>(tmp, offs, csr, NE);

  k_lin_in<<<NN / (4 * 4), 256, 0, stream>>>(x, W_in, b_in, h, rh);

  for (int l = 0; l < NLAYERS; l++) {
    k_agg<<<NN * 8 / 256, 256, 0, stream>>>(rh, csr, offs, cnt, agg);
    k_mlp<<<NN / 32, 256, 0, stream>>>(h, agg,
        W1 + (size_t)l * 64 * 128, b1 + (size_t)l * 128,
        gam + (size_t)l * 128, bet + (size_t)l * 128,
        W2 + (size_t)l * 128 * 64, b2 + (size_t)l * 64,
        eps + l, rh);
  }

  k_pool<<<SCAN_BLOCKS, 256, 0, stream>>>(h, batch, pooled, NN);
  k_out<<<1, 256, 0, stream>>>(pooled, Wo1, bo1, Wo2, bo2, out);
}

// Round 4
// 525.567 us; speedup vs baseline: 2.1209x; 1.4592x over previous
//
#include <hip/hip_runtime.h>
#include <hip/hip_bf16.h>

#define NN 100000
#define NE 1600000
#define DD 64
#define HH 128
#define NLAYERS 4
#define NGRAPH 64
#define NBUCKET 782        // ceil(NN/128) buckets of 128 dst nodes
#define NCHUNK 391         // ceil(NE/4096) edge chunks of 4096
#define NTOT (NBUCKET * NCHUNK)

typedef __attribute__((ext_vector_type(8))) short bf16x8;
typedef __attribute__((ext_vector_type(4))) float f32x4;

__device__ inline unsigned short bf16bits(float v) {
  return __bfloat16_as_ushort(__float2bfloat16(v));
}

// ---------------- CSR build ----------------

__global__ void k_count(const int* __restrict__ dst, int* __restrict__ cnt) {
  int e = blockIdx.x * 256 + threadIdx.x;
  atomicAdd(&cnt[dst[e]], 1);
}

__global__ void k_scan1(const int* __restrict__ in, int* __restrict__ out,
                        int* __restrict__ bsum, int n) {
  __shared__ int s[256];
  int t = threadIdx.x;
  int i = blockIdx.x * 256 + t;
  int v = (i < n) ? in[i] : 0;
  s[t] = v;
  __syncthreads();
  for (int off = 1; off < 256; off <<= 1) {
    int x = (t >= off) ? s[t - off] : 0;
    __syncthreads();
    s[t] += x;
    __syncthreads();
  }
  if (i < n) out[i] = s[t] - v;
  if (t == 255) bsum[blockIdx.x] = s[255];
}

__global__ void k_scan2(int* bsum, int nb) {
  __shared__ int s[512];
  int t = threadIdx.x;
  int v = (t < nb) ? bsum[t] : 0;
  s[t] = v;
  __syncthreads();
  for (int off = 1; off < 512; off <<= 1) {
    int x = (t >= off) ? s[t - off] : 0;
    __syncthreads();
    s[t] += x;
    __syncthreads();
  }
  if (t < nb) bsum[t] = s[t] - v;
}

__global__ void k_scan2b(int* bsum, int nb) {
  __shared__ int s[256];
  int t = threadIdx.x;
  int base = t * 5;
  int v[5];
  int sum = 0;
#pragma unroll
  for (int j = 0; j < 5; j++) {
    int i = base + j;
    v[j] = (i < nb) ? bsum[i] : 0;
    sum += v[j];
  }
  s[t] = sum;
  __syncthreads();
  for (int off = 1; off < 256; off <<= 1) {
    int x = (t >= off) ? s[t - off] : 0;
    __syncthreads();
    s[t] += x;
    __syncthreads();
  }
  int ex = s[t] - sum;
#pragma unroll
  for (int j = 0; j < 5; j++) {
    int i = base + j;
    if (i < nb) { int vv = v[j]; bsum[i] = ex; ex += vv; }
  }
}

__global__ void k_scan3(int* __restrict__ offs, const int* __restrict__ bsum, int n) {
  int i = blockIdx.x * 256 + threadIdx.x;
  if (i < n) offs[i] += bsum[i >> 8];
}

__global__ void k_hist(const int* __restrict__ dst, int* __restrict__ hist) {
  __shared__ int lh[NBUCKET];
  int t = threadIdx.x;
  int blk = blockIdx.x;
  for (int i = t; i < NBUCKET; i += 256) lh[i] = 0;
  __syncthreads();
  int cb = blk * 4096;
  int end = min(cb + 4096, NE);
  for (int i = cb + t; i < end; i += 256)
    atomicAdd(&lh[dst[i] >> 7], 1);
  __syncthreads();
  for (int i = t; i < NBUCKET; i += 256)
    hist[i * NCHUNK + blk] = lh[i];
}

__global__ void k_scatter(const int* __restrict__ src, const int* __restrict__ dst,
                          const int* __restrict__ hist, unsigned int* __restrict__ tmp) {
  __shared__ int lcur[NBUCKET];
  int t = threadIdx.x;
  int blk = blockIdx.x;
  for (int i = t; i < NBUCKET; i += 256) lcur[i] = hist[i * NCHUNK + blk];
  __syncthreads();
  int cb = blk * 4096;
  int end = min(cb + 4096, NE);
  for (int i = cb + t; i < end; i += 256) {
    int d = dst[i];
    int pos = atomicAdd(&lcur[d >> 7], 1);
    tmp[pos] = ((unsigned int)(d & 127) << 20) | (unsigned int)src[i];
  }
}

__global__ void k_fillB(const unsigned int* __restrict__ tmp,
                        const int* __restrict__ offs,
                        int* __restrict__ csr, int nedge) {
  __shared__ int lcur[128];
  int b = blockIdx.x;
  int t = threadIdx.x;
  int base = offs[b << 7];
  int end = (b == NBUCKET - 1) ? nedge : offs[(b + 1) << 7];
  if (t < 128) {
    int node = (b << 7) + t;
    lcur[t] = (node < NN) ? (offs[node] - base) : 0;
  }
  __syncthreads();
  for (int i = base + t; i < end; i += 256) {
    unsigned int v = tmp[i];
    int dl = v >> 20;
    int s = v & 0xFFFFF;
    int pos = atomicAdd(&lcur[dl], 1);
    csr[base + pos] = s;
  }
}

// ---------------- weight prep: bf16 transposed copies ----------------
// W1t[l][c][k] (128x64), W2t[l][c][k] (64x128)
__global__ void k_prep(const float* __restrict__ W1, const float* __restrict__ W2,
                       unsigned short* __restrict__ W1t, unsigned short* __restrict__ W2t) {
  int l = blockIdx.x >> 1;
  int m = blockIdx.x & 1;
  int t = threadIdx.x;
  if (m == 0) {
    const float* src = W1 + (size_t)l * 8192;
    unsigned short* dstp = W1t + (size_t)l * 8192;
    for (int i = t; i < 8192; i += 256) {
      int c = i >> 6, k = i & 63;
      dstp[i] = bf16bits(src[k * 128 + c]);
    }
  } else {
    const float* src = W2 + (size_t)l * 8192;
    unsigned short* dstp = W2t + (size_t)l * 8192;
    for (int i = t; i < 8192; i += 256) {
      int c = i >> 7, k = i & 127;
      dstp[i] = bf16bits(src[k * 64 + c]);
    }
  }
}

// ---------------- lin_in: h = x @ W_in + b_in ; rh = bf16(relu(h)) ----------------
__global__ void k_lin_in(const float* __restrict__ x, const float* __restrict__ W,
                         const float* __restrict__ b, float* __restrict__ h,
                         unsigned short* __restrict__ rh) {
  int t = threadIdx.x;
  int c = t & 63;
  int wv = blockIdx.x * 4 + (t >> 6);
  int n0 = wv * 4;
  float bc = b[c];
  float a0 = bc, a1 = bc, a2 = bc, a3 = bc;
  const float* x0 = x + n0 * 64;
#pragma unroll 8
  for (int k = 0; k < 64; k++) {
    float w = W[k * 64 + c];
    a0 += x0[k] * w;
    a1 += x0[64 + k] * w;
    a2 += x0[128 + k] * w;
    a3 += x0[192 + k] * w;
  }
  h[(n0 + 0) * 64 + c] = a0;
  h[(n0 + 1) * 64 + c] = a1;
  h[(n0 + 2) * 64 + c] = a2;
  h[(n0 + 3) * 64 + c] = a3;
  rh[(n0 + 0) * 64 + c] = bf16bits(fmaxf(a0, 0.f));
  rh[(n0 + 1) * 64 + c] = bf16bits(fmaxf(a1, 0.f));
  rh[(n0 + 2) * 64 + c] = bf16bits(fmaxf(a2, 0.f));
  rh[(n0 + 3) * 64 + c] = bf16bits(fmaxf(a3, 0.f));
}

// ---------------- aggregate: agg[i] = sum_{e: dst=i} rh[src] ----------------
// 8 threads/node; edge indices loaded once per 8 and shared via shfl
__global__ void k_agg(const unsigned short* __restrict__ rh,
                      const int* __restrict__ csr, const int* __restrict__ offs,
                      const int* __restrict__ cnt, unsigned short* __restrict__ agg) {
  int t = blockIdx.x * 256 + threadIdx.x;
  int node = t >> 3;
  int lane8 = t & 7;
  int part = lane8 * 8;
  int start = offs[node];
  int deg = cnt[node];
  float acc[8] = {0.f, 0.f, 0.f, 0.f, 0.f, 0.f, 0.f, 0.f};
  for (int j0 = 0; j0 < deg; j0 += 8) {
    int myj = j0 + lane8;
    int idx = (myj < deg) ? csr[start + myj] : 0;
    int c8 = min(deg - j0, 8);
    for (int jj = 0; jj < c8; jj++) {
      int s = __shfl(idx, jj, 8);
      uint4 v = *reinterpret_cast<const uint4*>(rh + (size_t)s * 64 + part);
      acc[0] += __uint_as_float(v.x << 16);
      acc[1] += __uint_as_float(v.x & 0xFFFF0000u);
      acc[2] += __uint_as_float(v.y << 16);
      acc[3] += __uint_as_float(v.y & 0xFFFF0000u);
      acc[4] += __uint_as_float(v.z << 16);
      acc[5] += __uint_as_float(v.z & 0xFFFF0000u);
      acc[6] += __uint_as_float(v.w << 16);
      acc[7] += __uint_as_float(v.w & 0xFFFF0000u);
    }
  }
  ushort4 o0, o1;
  o0.x = bf16bits(acc[0]); o0.y = bf16bits(acc[1]);
  o0.z = bf16bits(acc[2]); o0.w = bf16bits(acc[3]);
  o1.x = bf16bits(acc[4]); o1.y = bf16bits(acc[5]);
  o1.z = bf16bits(acc[6]); o1.w = bf16bits(acc[7]);
  *reinterpret_cast<ushort4*>(agg + (size_t)node * 64 + part) = o0;
  *reinterpret_cast<ushort4*>(agg + (size_t)node * 64 + part + 4) = o1;
}

// ---------------- fused MFMA MLP per layer ----------------
// 64 nodes/block, 4 waves. GEMM1: Z[64x64]@W1[64x128]; LN+relu in-register;
// sR LDS round-trip (swizzled); GEMM2: R[64x128]@W2[128x64]; h += .., rh = relu.
__global__ __launch_bounds__(256) void k_mlp(
    float* __restrict__ h, const unsigned short* __restrict__ agg,
    const unsigned short* __restrict__ W1t, const float* __restrict__ b1l,
    const float* __restrict__ gl, const float* __restrict__ btl,
    const unsigned short* __restrict__ W2t, const float* __restrict__ b2l,
    const float* __restrict__ epsl, unsigned short* __restrict__ rh) {
  __shared__ __align__(16) unsigned short sW1[8192];  // [c=128][8 slots swz]
  __shared__ __align__(16) unsigned short sW2[8192];  // [c=64][16 slots swz]
  __shared__ __align__(16) unsigned short sRr[8192];  // [r=64][16 slots swz]
  __shared__ float sb1[128], sg[128], sbt[128], sb2[64];

  int t = threadIdx.x;
  int nbase = blockIdx.x * 64;
  int l = t & 63;
  int w = t >> 6;
  int lm = l & 15;
  int lk = l >> 4;

  // stage weights (swizzled 16B slots)
  {
    const uint4* w1g = (const uint4*)W1t;
    uint4* sW1u = (uint4*)sW1;
    for (int g = t; g < 1024; g += 256) {
      int c = g >> 3, s = g & 7;
      sW1u[c * 8 + (s ^ (c & 7))] = w1g[g];
    }
    const uint4* w2g = (const uint4*)W2t;
    uint4* sW2u = (uint4*)sW2;
    for (int g = t; g < 1024; g += 256) {
      int c = g >> 4, s = g & 15;
      sW2u[c * 16 + (s ^ (c & 15))] = w2g[g];
    }
    if (t < 128) { sb1[t] = b1l[t]; sg[t] = gl[t]; sbt[t] = btl[t]; }
    if (t < 64) sb2[t] = b2l[t];
  }
  float epsv = 1.0f + *epsl;

  // A-frags for GEMM1 directly from global (z never materialized)
  int rowl = w * 16 + lm;                 // block-local row (GEMM1-A / GEMM2-A)
  int grow = nbase + rowl;
  int growc = min(grow, NN - 1);
  bf16x8 a1[2];
#pragma unroll
  for (int kb = 0; kb < 2; kb++) {
    int d0 = kb * 32 + lk * 8;
    const float* hp = &h[(size_t)growc * 64 + d0];
    float4 h0 = *(const float4*)hp;
    float4 h1 = *(const float4*)(hp + 4);
    uint4 av = *(const uint4*)&agg[(size_t)growc * 64 + d0];
    float z[8];
    z[0] = epsv * h0.x + __uint_as_float(av.x << 16);
    z[1] = epsv * h0.y + __uint_as_float(av.x & 0xFFFF0000u);
    z[2] = epsv * h0.z + __uint_as_float(av.y << 16);
    z[3] = epsv * h0.w + __uint_as_float(av.y & 0xFFFF0000u);
    z[4] = epsv * h1.x + __uint_as_float(av.z << 16);
    z[5] = epsv * h1.y + __uint_as_float(av.z & 0xFFFF0000u);
    z[6] = epsv * h1.z + __uint_as_float(av.w << 16);
    z[7] = epsv * h1.w + __uint_as_float(av.w & 0xFFFF0000u);
#pragma unroll
    for (int j = 0; j < 8; j++) a1[kb][j] = (short)bf16bits(z[j]);
  }
  __syncthreads();

  // GEMM1: acc1[n] over 8 col-tiles
  f32x4 acc1[8];
#pragma unroll
  for (int n = 0; n < 8; n++) {
    float bc = sb1[n * 16 + lm];
    acc1[n] = (f32x4){bc, bc, bc, bc};
  }
  {
    const bf16x8* sW1f = (const bf16x8*)sW1;
#pragma unroll
    for (int n = 0; n < 8; n++) {
      int c = n * 16 + lm;
      bf16x8 b0 = sW1f[c * 8 + ((0 * 4 + lk) ^ (c & 7))];
      bf16x8 b1f = sW1f[c * 8 + ((1 * 4 + lk) ^ (c & 7))];
      acc1[n] = __builtin_amdgcn_mfma_f32_16x16x32_bf16(a1[0], b0, acc1[n], 0, 0, 0);
      acc1[n] = __builtin_amdgcn_mfma_f32_16x16x32_bf16(a1[1], b1f, acc1[n], 0, 0, 0);
    }
  }

  // LayerNorm + relu on D-frags (row = lk*4+r within tile), write swizzled sR
  float psr[4], pqr[4];
#pragma unroll
  for (int r = 0; r < 4; r++) {
    float s = 0.f, q = 0.f;
#pragma unroll
    for (int n = 0; n < 8; n++) { float v = acc1[n][r]; s += v; q += v * v; }
    psr[r] = s; pqr[r] = q;
  }
#pragma unroll
  for (int m = 1; m <= 8; m <<= 1) {
#pragma unroll
    for (int r = 0; r < 4; r++) {
      psr[r] += __shfl_xor(psr[r], m);
      pqr[r] += __shfl_xor(pqr[r], m);
    }
  }
#pragma unroll
  for (int r = 0; r < 4; r++) {
    float mu = psr[r] * (1.0f / 128.0f);
    float var = pqr[r] * (1.0f / 128.0f) - mu * mu;
    float rs = rsqrtf(var + 1e-5f);
    int rowr = w * 16 + lk * 4 + r;
#pragma unroll
    for (int n = 0; n < 8; n++) {
      int c = n * 16 + lm;
      float v = (acc1[n][r] - mu) * rs * sg[c] + sbt[c];
      v = fmaxf(v, 0.f);
      int slot = (c >> 3) ^ (rowr & 7);
      sRr[rowr * 128 + slot * 8 + (c & 7)] = bf16bits(v);
    }
  }
  __syncthreads();

  // GEMM2
  f32x4 acc2[4];
#pragma unroll
  for (int n2 = 0; n2 < 4; n2++) {
    float bc = sb2[n2 * 16 + lm];
    acc2[n2] = (f32x4){bc, bc, bc, bc};
  }
  {
    const bf16x8* sRf = (const bf16x8*)sRr;
    const bf16x8* sW2f = (const bf16x8*)sW2;
    bf16x8 a2[4];
#pragma unroll
    for (int kb = 0; kb < 4; kb++)
      a2[kb] = sRf[rowl * 16 + ((kb * 4 + lk) ^ (rowl & 7))];
#pragma unroll
    for (int n2 = 0; n2 < 4; n2++) {
      int c = n2 * 16 + lm;
#pragma unroll
      for (int kb = 0; kb < 4; kb++) {
        bf16x8 bfr = sW2f[c * 16 + ((kb * 4 + lk) ^ (c & 15))];
        acc2[n2] = __builtin_amdgcn_mfma_f32_16x16x32_bf16(a2[kb], bfr, acc2[n2], 0, 0, 0);
      }
    }
  }

  // epilogue: h += out + b2 ; rh = bf16(relu(h))
#pragma unroll
  for (int r = 0; r < 4; r++) {
    int grow2 = nbase + w * 16 + lk * 4 + r;
    if (grow2 < NN) {
#pragma unroll
      for (int n2 = 0; n2 < 4; n2++) {
        int c = n2 * 16 + lm;
        size_t idx = (size_t)grow2 * 64 + c;
        float o = h[idx] + acc2[n2][r];
        h[idx] = o;
        rh[idx] = bf16bits(fmaxf(o, 0.f));
      }
    }
  }
}

// ---------------- pooling ----------------
__global__ void k_pool(const float* __restrict__ h, const int* __restrict__ batch,
                       float* __restrict__ pooled, int n) {
  int t = threadIdx.x;
  int d = t & 63;
  int w = t >> 6;
  int n0 = blockIdx.x * 256 + w * 64;
  float acc = 0.f;
  int prev = -1;
  for (int i = 0; i < 64; i++) {
    int nn = n0 + i;
    if (nn >= n) break;
    int g = batch[nn];
    if (g != prev) {
      if (prev >= 0) atomicAdd(&pooled[prev * 64 + d], acc);
      prev = g;
      acc = 0.f;
    }
    acc += h[(size_t)nn * 64 + d];
  }
  if (prev >= 0) atomicAdd(&pooled[prev * 64 + d], acc);
}

// ---------------- output MLP ----------------
__global__ void k_out(const float* __restrict__ pooled, const float* __restrict__ Wo1,
                      const float* __restrict__ bo1, const float* __restrict__ Wo2,
                      const float* __restrict__ bo2, float* __restrict__ out) {
  __shared__ __align__(16) float sP[64 * 64];
  int t = threadIdx.x;
  for (int i = t; i < 1024; i += 256)
    ((float4*)sP)[i] = ((const float4*)pooled)[i];
  __syncthreads();
  int g = t >> 2;
  int q = t & 3;
  float acc = 0.f;
  for (int c = q * 32; c < q * 32 + 32; c++) {
    float t1 = bo1[c];
#pragma unroll 8
    for (int k = 0; k < 64; k++) t1 += sP[g * 64 + k] * Wo1[k * 128 + c];
    acc += fmaxf(t1, 0.f) * Wo2[c];
  }
  acc += __shfl_xor(acc, 1);
  acc += __shfl_xor(acc, 2);
  if (q == 0) out[g] = acc + bo2[0];
}

// ---------------- launch ----------------

static inline char* align_up(char* p, size_t a) {
  return (char*)(((uintptr_t)p + a - 1) & ~(uintptr_t)(a - 1));
}

extern "C" void kernel_launch(void* const* d_in, const int* in_sizes, int n_in,
                              void* d_out, int out_size, void* d_ws, size_t ws_size,
                              hipStream_t stream) {
  const float* x    = (const float*)d_in[0];
  const float* W_in = (const float*)d_in[1];
  const float* b_in = (const float*)d_in[2];
  const float* eps  = (const float*)d_in[3];
  const float* W1   = (const float*)d_in[4];
  const float* b1   = (const float*)d_in[5];
  const float* gam  = (const float*)d_in[6];
  const float* bet  = (const float*)d_in[7];
  const float* W2   = (const float*)d_in[8];
  const float* b2   = (const float*)d_in[9];
  const float* Wo1  = (const float*)d_in[10];
  const float* bo1  = (const float*)d_in[11];
  const float* Wo2  = (const float*)d_in[12];
  const float* bo2  = (const float*)d_in[13];
  const int* ei     = (const int*)d_in[14];
  const int* batch  = (const int*)d_in[15];
  float* out = (float*)d_out;

  const int* e_src = ei;
  const int* e_dst = ei + NE;

  char* p = (char*)d_ws;
  float* h = (float*)p;              p += (size_t)NN * 64 * 4;     // 25.6 MB
  unsigned short* agg = (unsigned short*)p;
  unsigned int* tmp = (unsigned int*)p;   // aliases agg (disjoint in time)
                                     p += (size_t)NN * 64 * 2;     // 12.8 MB
  unsigned short* rh = (unsigned short*)p; p += (size_t)NN * 64 * 2; // 12.8 MB
  int* csr = (int*)p;
  int* hist = (int*)p;               // aliases csr (hist dead before fillB)
                                     p += (size_t)NE * 4;          // 6.4 MB
  int* cnt = (int*)p;                p += (size_t)NN * 4;
  int* offs = (int*)p;               p += (size_t)NN * 4;
  int* bsum = (int*)p;               p += 512 * 4;
  int* bsumH = (int*)p;              p += 1280 * 4;
  p = align_up(p, 256);
  float* pooled = (float*)p;         p += (size_t)NGRAPH * 64 * 4;
  p = align_up(p, 256);
  unsigned short* W1t = (unsigned short*)p; p += (size_t)NLAYERS * 8192 * 2;
  unsigned short* W2t = (unsigned short*)p; p += (size_t)NLAYERS * 8192 * 2;

  const int SCAN_BLOCKS = (NN + 255) / 256;          // 391
  const int SCAN_BLOCKS_H = (NTOT + 255) / 256;      // 1195

  hipMemsetAsync(cnt, 0, (size_t)NN * 4, stream);
  hipMemsetAsync(pooled, 0, (size_t)NGRAPH * 64 * 4, stream);

  // node-level degree + offsets
  k_count<<<NE / 256, 256, 0, stream>>>(e_dst, cnt);
  k_scan1<<<SCAN_BLOCKS, 256, 0, stream>>>(cnt, offs, bsum, NN);
  k_scan2<<<1, 512, 0, stream>>>(bsum, SCAN_BLOCKS);
  k_scan3<<<SCAN_BLOCKS, 256, 0, stream>>>(offs, bsum, NN);

  // bucket-level counting sort (atomic-free reservation)
  k_hist<<<NCHUNK, 256, 0, stream>>>(e_dst, hist);
  k_scan1<<<SCAN_BLOCKS_H, 256, 0, stream>>>(hist, hist, bsumH, NTOT);
  k_scan2b<<<1, 256, 0, stream>>>(bsumH, SCAN_BLOCKS_H);
  k_scan3<<<SCAN_BLOCKS_H, 256, 0, stream>>>(hist, bsumH, NTOT);
  k_scatter<<<NCHUNK, 256, 0, stream>>>(e_src, e_dst, hist, tmp);
  k_fillB<<<NBUCKET, 256, 0, stream>>>(tmp, offs, csr, NE);

  // weight prep + lin_in
  k_prep<<<NLAYERS * 2, 256, 0, stream>>>(W1, W2, W1t, W2t);
  k_lin_in<<<NN / (4 * 4), 256, 0, stream>>>(x, W_in, b_in, h, rh);

  for (int l = 0; l < NLAYERS; l++) {
    k_agg<<<NN * 8 / 256, 256, 0, stream>>>(rh, csr, offs, cnt, agg);
    k_mlp<<<(NN + 63) / 64, 256, 0, stream>>>(h, agg,
        W1t + (size_t)l * 8192, b1 + (size_t)l * 128,
        gam + (size_t)l * 128, bet + (size_t)l * 128,
        W2t + (size_t)l * 8192, b2 + (size_t)l * 64,
        eps + l, rh);
  }

  k_pool<<<SCAN_BLOCKS, 256, 0, stream>>>(h, batch, pooled, NN);
  k_out<<<1, 256, 0, stream>>>(pooled, Wo1, bo1, Wo2, bo2, out);
}

// Round 5
// 439.736 us; speedup vs baseline: 2.5348x; 1.1952x over previous
//
#include <hip/hip_runtime.h>
#include <hip/hip_bf16.h>

#define NN 100000
#define NE 1600000
#define DD 64
#define HH 128
#define NLAYERS 4
#define NGRAPH 64
#define NBUCKET 782        // ceil(NN/128) buckets of 128 dst nodes
#define NCHUNK 391         // ceil(NE/4096) edge chunks of 4096
#define NTOT (NBUCKET * NCHUNK)

typedef __attribute__((ext_vector_type(8))) short bf16x8;
typedef __attribute__((ext_vector_type(4))) float f32x4;

__device__ inline unsigned short bf16bits(float v) {
  return __bfloat16_as_ushort(__float2bfloat16(v));
}

// ---------------- CSR build ----------------

__global__ void k_hist(const int* __restrict__ dst, int* __restrict__ hist) {
  __shared__ int lh[NBUCKET];
  int t = threadIdx.x;
  int blk = blockIdx.x;
  for (int i = t; i < NBUCKET; i += 256) lh[i] = 0;
  __syncthreads();
  int cb = blk * 4096;
  int end = min(cb + 4096, NE);
  for (int i = cb + t; i < end; i += 256)
    atomicAdd(&lh[dst[i] >> 7], 1);
  __syncthreads();
  for (int i = t; i < NBUCKET; i += 256)
    hist[i * NCHUNK + blk] = lh[i];
}

__global__ void k_scan1(const int* __restrict__ in, int* __restrict__ out,
                        int* __restrict__ bsum, int n) {
  __shared__ int s[256];
  int t = threadIdx.x;
  int i = blockIdx.x * 256 + t;
  int v = (i < n) ? in[i] : 0;
  s[t] = v;
  __syncthreads();
  for (int off = 1; off < 256; off <<= 1) {
    int x = (t >= off) ? s[t - off] : 0;
    __syncthreads();
    s[t] += x;
    __syncthreads();
  }
  if (i < n) out[i] = s[t] - v;
  if (t == 255) bsum[blockIdx.x] = s[255];
}

__global__ void k_scan2b(int* bsum, int nb) {
  __shared__ int s[256];
  int t = threadIdx.x;
  int base = t * 5;
  int v[5];
  int sum = 0;
#pragma unroll
  for (int j = 0; j < 5; j++) {
    int i = base + j;
    v[j] = (i < nb) ? bsum[i] : 0;
    sum += v[j];
  }
  s[t] = sum;
  __syncthreads();
  for (int off = 1; off < 256; off <<= 1) {
    int x = (t >= off) ? s[t - off] : 0;
    __syncthreads();
    s[t] += x;
    __syncthreads();
  }
  int ex = s[t] - sum;
#pragma unroll
  for (int j = 0; j < 5; j++) {
    int i = base + j;
    if (i < nb) { int vv = v[j]; bsum[i] = ex; ex += vv; }
  }
}

// finalize hist offsets + extract per-bucket bases (avoids hist/csr alias race)
__global__ void k_scan3b(int* __restrict__ hist, const int* __restrict__ bsum,
                         int* __restrict__ bbase, int n) {
  int i = blockIdx.x * 256 + threadIdx.x;
  if (i < n) {
    int v = hist[i] + bsum[i >> 8];
    hist[i] = v;
    if (i % NCHUNK == 0) bbase[i / NCHUNK] = v;
  }
}

__global__ void k_scatter(const int* __restrict__ src, const int* __restrict__ dst,
                          const int* __restrict__ hist, unsigned int* __restrict__ tmp) {
  __shared__ int lcur[NBUCKET];
  int t = threadIdx.x;
  int blk = blockIdx.x;
  for (int i = t; i < NBUCKET; i += 256) lcur[i] = hist[i * NCHUNK + blk];
  __syncthreads();
  int cb = blk * 4096;
  int end = min(cb + 4096, NE);
  for (int i = cb + t; i < end; i += 256) {
    int d = dst[i];
    int pos = atomicAdd(&lcur[d >> 7], 1);
    tmp[pos] = ((unsigned int)(d & 127) << 20) | (unsigned int)src[i];
  }
}

// per-bucket: derive per-node offs/cnt (LDS count+scan), then place edges
__global__ void k_fillB2(const unsigned int* __restrict__ tmp,
                         const int* __restrict__ bbase,
                         int* __restrict__ csr, int* __restrict__ offs,
                         int* __restrict__ cnt) {
  __shared__ int lcnt[128], lex[128], lcur[128];
  int b = blockIdx.x;
  int t = threadIdx.x;
  int base = bbase[b];
  int end = (b == NBUCKET - 1) ? NE : bbase[b + 1];
  if (t < 128) lcnt[t] = 0;
  __syncthreads();
  for (int i = base + t; i < end; i += 256)
    atomicAdd(&lcnt[tmp[i] >> 20], 1);
  __syncthreads();
  int v = (t < 128) ? lcnt[t] : 0;
  if (t < 128) lex[t] = v;
  __syncthreads();
  for (int off = 1; off < 128; off <<= 1) {
    int x = (t >= off && t < 128) ? lex[t - off] : 0;
    __syncthreads();
    if (t < 128) lex[t] += x;
    __syncthreads();
  }
  if (t < 128) {
    int ex = lex[t] - v;
    lcur[t] = ex;
    int node = (b << 7) + t;
    if (node < NN) { offs[node] = base + ex; cnt[node] = v; }
  }
  __syncthreads();
  for (int i = base + t; i < end; i += 256) {
    unsigned int u = tmp[i];
    int dl = u >> 20;
    int pos = atomicAdd(&lcur[dl], 1);
    csr[base + pos] = u & 0xFFFFF;
  }
}

// ---------------- weight prep: bf16 transposed copies ----------------
__global__ void k_prep(const float* __restrict__ W1, const float* __restrict__ W2,
                       const float* __restrict__ W_in,
                       unsigned short* __restrict__ W1t, unsigned short* __restrict__ W2t,
                       unsigned short* __restrict__ Wint) {
  int bidx = blockIdx.x;
  int t = threadIdx.x;
  if (bidx == 2 * NLAYERS) {
    for (int i = t; i < 4096; i += 256) {
      int c = i >> 6, k = i & 63;
      Wint[i] = bf16bits(W_in[k * 64 + c]);
    }
    return;
  }
  int l = bidx >> 1;
  int m = bidx & 1;
  if (m == 0) {
    const float* src = W1 + (size_t)l * 8192;
    unsigned short* dstp = W1t + (size_t)l * 8192;
    for (int i = t; i < 8192; i += 256) {
      int c = i >> 6, k = i & 63;
      dstp[i] = bf16bits(src[k * 128 + c]);
    }
  } else {
    const float* src = W2 + (size_t)l * 8192;
    unsigned short* dstp = W2t + (size_t)l * 8192;
    for (int i = t; i < 8192; i += 256) {
      int c = i >> 7, k = i & 127;
      dstp[i] = bf16bits(src[k * 64 + c]);
    }
  }
}

// ---------------- lin_in via MFMA: h = x @ W_in + b_in ; rh = bf16(relu(h)) -------
__global__ __launch_bounds__(256) void k_lin(
    const float* __restrict__ x, const unsigned short* __restrict__ Wint,
    const float* __restrict__ binp, float* __restrict__ h,
    unsigned short* __restrict__ rh) {
  __shared__ __align__(16) unsigned short sW[4096];   // [c=64][8 slots swz]
  __shared__ float sb[64];
  int t = threadIdx.x;
  {
    const uint4* wg = (const uint4*)Wint;
    uint4* sWu = (uint4*)sW;
    for (int g = t; g < 512; g += 256) {
      int c = g >> 3, s = g & 7;
      sWu[c * 8 + (s ^ (c & 7))] = wg[g];
    }
    if (t < 64) sb[t] = binp[t];
  }
  int l = t & 63, w = t >> 6, lm = l & 15, lk = l >> 4;
  int rowl = w * 16 + lm;
  int grow = blockIdx.x * 64 + rowl;
  int growc = min(grow, NN - 1);
  bf16x8 a[2];
#pragma unroll
  for (int kb = 0; kb < 2; kb++) {
    const float* xp = &x[(size_t)growc * 64 + kb * 32 + lk * 8];
    float4 x0 = *(const float4*)xp;
    float4 x1 = *(const float4*)(xp + 4);
    a[kb][0] = (short)bf16bits(x0.x); a[kb][1] = (short)bf16bits(x0.y);
    a[kb][2] = (short)bf16bits(x0.z); a[kb][3] = (short)bf16bits(x0.w);
    a[kb][4] = (short)bf16bits(x1.x); a[kb][5] = (short)bf16bits(x1.y);
    a[kb][6] = (short)bf16bits(x1.z); a[kb][7] = (short)bf16bits(x1.w);
  }
  __syncthreads();
  f32x4 acc[4];
#pragma unroll
  for (int n = 0; n < 4; n++) {
    float bc = sb[n * 16 + lm];
    acc[n] = (f32x4){bc, bc, bc, bc};
  }
  const bf16x8* sWf = (const bf16x8*)sW;
#pragma unroll
  for (int n = 0; n < 4; n++) {
    int c = n * 16 + lm;
    bf16x8 b0 = sWf[c * 8 + ((0 * 4 + lk) ^ (c & 7))];
    bf16x8 b1 = sWf[c * 8 + ((1 * 4 + lk) ^ (c & 7))];
    acc[n] = __builtin_amdgcn_mfma_f32_16x16x32_bf16(a[0], b0, acc[n], 0, 0, 0);
    acc[n] = __builtin_amdgcn_mfma_f32_16x16x32_bf16(a[1], b1, acc[n], 0, 0, 0);
  }
#pragma unroll
  for (int r = 0; r < 4; r++) {
    int grow2 = blockIdx.x * 64 + w * 16 + lk * 4 + r;
    if (grow2 < NN) {
#pragma unroll
      for (int n = 0; n < 4; n++) {
        int c = n * 16 + lm;
        size_t idx = (size_t)grow2 * 64 + c;
        float o = acc[n][r];
        h[idx] = o;
        rh[idx] = bf16bits(fmaxf(o, 0.f));
      }
    }
  }
}

// ---------------- fused layer: gather + MLP (MFMA) ----------------
// 64 nodes/block, 4 waves. Gather agg into regs (4 threads/node, 16 dims each),
// z = (1+eps)*h + agg -> A-frags; GEMM1; LN+relu; sR roundtrip; GEMM2;
// h += out; rhout = bf16(relu(h)).
__global__ __launch_bounds__(256) void k_fused(
    float* __restrict__ h, const unsigned short* __restrict__ rhin,
    unsigned short* __restrict__ rhout,
    const int* __restrict__ csr, const int* __restrict__ offs,
    const int* __restrict__ cnt,
    const unsigned short* __restrict__ W1t, const float* __restrict__ b1l,
    const float* __restrict__ gl, const float* __restrict__ btl,
    const unsigned short* __restrict__ W2t, const float* __restrict__ b2l,
    const float* __restrict__ epsl) {
  __shared__ __align__(16) unsigned short sW1[8192];  // [c=128][8 slots swz]
  __shared__ __align__(16) unsigned short sW2[8192];  // [c=64][16 slots swz]
  __shared__ __align__(16) unsigned short sRr[8192];  // [r=64][16 slots swz]
  __shared__ float sb1[128], sg[128], sbt[128], sb2[64];

  int t = threadIdx.x;
  int nbase = blockIdx.x * 64;
  int l = t & 63;
  int w = t >> 6;
  int lm = l & 15;
  int lk = l >> 4;

  // stage weights (swizzled 16B slots)
  {
    const uint4* w1g = (const uint4*)W1t;
    uint4* sW1u = (uint4*)sW1;
    for (int g = t; g < 1024; g += 256) {
      int c = g >> 3, s = g & 7;
      sW1u[c * 8 + (s ^ (c & 7))] = w1g[g];
    }
    const uint4* w2g = (const uint4*)W2t;
    uint4* sW2u = (uint4*)sW2;
    for (int g = t; g < 1024; g += 256) {
      int c = g >> 4, s = g & 15;
      sW2u[c * 16 + (s ^ (c & 15))] = w2g[g];
    }
    if (t < 128) { sb1[t] = b1l[t]; sg[t] = gl[t]; sbt[t] = btl[t]; }
    if (t < 64) sb2[t] = b2l[t];
  }
  float epsv = 1.0f + *epsl;

  // ---- gather phase: agg for own node rows, 16 dims per thread ----
  int rowl = w * 16 + lm;
  int grow = nbase + rowl;
  int growc = min(grow, NN - 1);
  int start = offs[growc];
  int deg = (grow < NN) ? cnt[growc] : 0;
  float accA[8] = {0.f, 0.f, 0.f, 0.f, 0.f, 0.f, 0.f, 0.f};
  float accB[8] = {0.f, 0.f, 0.f, 0.f, 0.f, 0.f, 0.f, 0.f};
  for (int j0 = 0; j0 < deg; j0 += 4) {
    int myj = j0 + lk;
    int idx = (myj < deg) ? csr[start + myj] : 0;
    int c4 = min(deg - j0, 4);
    for (int jj = 0; jj < c4; jj++) {
      int s = __shfl(idx, lm + jj * 16);
      const unsigned short* rp = rhin + (size_t)s * 64 + lk * 8;
      uint4 vA = *(const uint4*)rp;
      uint4 vB = *(const uint4*)(rp + 32);
      accA[0] += __uint_as_float(vA.x << 16);
      accA[1] += __uint_as_float(vA.x & 0xFFFF0000u);
      accA[2] += __uint_as_float(vA.y << 16);
      accA[3] += __uint_as_float(vA.y & 0xFFFF0000u);
      accA[4] += __uint_as_float(vA.z << 16);
      accA[5] += __uint_as_float(vA.z & 0xFFFF0000u);
      accA[6] += __uint_as_float(vA.w << 16);
      accA[7] += __uint_as_float(vA.w & 0xFFFF0000u);
      accB[0] += __uint_as_float(vB.x << 16);
      accB[1] += __uint_as_float(vB.x & 0xFFFF0000u);
      accB[2] += __uint_as_float(vB.y << 16);
      accB[3] += __uint_as_float(vB.y & 0xFFFF0000u);
      accB[4] += __uint_as_float(vB.z << 16);
      accB[5] += __uint_as_float(vB.z & 0xFFFF0000u);
      accB[6] += __uint_as_float(vB.w << 16);
      accB[7] += __uint_as_float(vB.w & 0xFFFF0000u);
    }
  }

  // z = (1+eps)*h + agg -> A-frags
  bf16x8 a1[2];
  {
    const float* hp = &h[(size_t)growc * 64 + lk * 8];
#pragma unroll
    for (int j = 0; j < 8; j++)
      a1[0][j] = (short)bf16bits(epsv * hp[j] + accA[j]);
    const float* hp2 = hp + 32;
#pragma unroll
    for (int j = 0; j < 8; j++)
      a1[1][j] = (short)bf16bits(epsv * hp2[j] + accB[j]);
  }
  __syncthreads();

  // GEMM1: acc1[n] over 8 col-tiles
  f32x4 acc1[8];
#pragma unroll
  for (int n = 0; n < 8; n++) {
    float bc = sb1[n * 16 + lm];
    acc1[n] = (f32x4){bc, bc, bc, bc};
  }
  {
    const bf16x8* sW1f = (const bf16x8*)sW1;
#pragma unroll
    for (int n = 0; n < 8; n++) {
      int c = n * 16 + lm;
      bf16x8 b0 = sW1f[c * 8 + ((0 * 4 + lk) ^ (c & 7))];
      bf16x8 b1f = sW1f[c * 8 + ((1 * 4 + lk) ^ (c & 7))];
      acc1[n] = __builtin_amdgcn_mfma_f32_16x16x32_bf16(a1[0], b0, acc1[n], 0, 0, 0);
      acc1[n] = __builtin_amdgcn_mfma_f32_16x16x32_bf16(a1[1], b1f, acc1[n], 0, 0, 0);
    }
  }

  // LayerNorm + relu on D-frags, write swizzled sR
  float psr[4], pqr[4];
#pragma unroll
  for (int r = 0; r < 4; r++) {
    float s = 0.f, q = 0.f;
#pragma unroll
    for (int n = 0; n < 8; n++) { float v = acc1[n][r]; s += v; q += v * v; }
    psr[r] = s; pqr[r] = q;
  }
#pragma unroll
  for (int m = 1; m <= 8; m <<= 1) {
#pragma unroll
    for (int r = 0; r < 4; r++) {
      psr[r] += __shfl_xor(psr[r], m);
      pqr[r] += __shfl_xor(pqr[r], m);
    }
  }
#pragma unroll
  for (int r = 0; r < 4; r++) {
    float mu = psr[r] * (1.0f / 128.0f);
    float var = pqr[r] * (1.0f / 128.0f) - mu * mu;
    float rs = rsqrtf(var + 1e-5f);
    int rowr = w * 16 + lk * 4 + r;
#pragma unroll
    for (int n = 0; n < 8; n++) {
      int c = n * 16 + lm;
      float v = (acc1[n][r] - mu) * rs * sg[c] + sbt[c];
      v = fmaxf(v, 0.f);
      int slot = (c >> 3) ^ (rowr & 7);
      sRr[rowr * 128 + slot * 8 + (c & 7)] = bf16bits(v);
    }
  }
  __syncthreads();

  // GEMM2
  f32x4 acc2[4];
#pragma unroll
  for (int n2 = 0; n2 < 4; n2++) {
    float bc = sb2[n2 * 16 + lm];
    acc2[n2] = (f32x4){bc, bc, bc, bc};
  }
  {
    const bf16x8* sRf = (const bf16x8*)sRr;
    const bf16x8* sW2f = (const bf16x8*)sW2;
    bf16x8 a2[4];
#pragma unroll
    for (int kb = 0; kb < 4; kb++)
      a2[kb] = sRf[rowl * 16 + ((kb * 4 + lk) ^ (rowl & 7))];
#pragma unroll
    for (int n2 = 0; n2 < 4; n2++) {
      int c = n2 * 16 + lm;
#pragma unroll
      for (int kb = 0; kb < 4; kb++) {
        bf16x8 bfr = sW2f[c * 16 + ((kb * 4 + lk) ^ (c & 15))];
        acc2[n2] = __builtin_amdgcn_mfma_f32_16x16x32_bf16(a2[kb], bfr, acc2[n2], 0, 0, 0);
      }
    }
  }

  // epilogue: h += out + b2 ; rhout = bf16(relu(h))
#pragma unroll
  for (int r = 0; r < 4; r++) {
    int grow2 = nbase + w * 16 + lk * 4 + r;
    if (grow2 < NN) {
#pragma unroll
      for (int n2 = 0; n2 < 4; n2++) {
        int c = n2 * 16 + lm;
        size_t idx = (size_t)grow2 * 64 + c;
        float o = h[idx] + acc2[n2][r];
        h[idx] = o;
        rhout[idx] = bf16bits(fmaxf(o, 0.f));
      }
    }
  }
}

// ---------------- pooling ----------------
__global__ void k_pool(const float* __restrict__ h, const int* __restrict__ batch,
                       float* __restrict__ pooled, int n) {
  int t = threadIdx.x;
  int d = t & 63;
  int w = t >> 6;
  int n0 = blockIdx.x * 256 + w * 64;
  float acc = 0.f;
  int prev = -1;
  for (int i = 0; i < 64; i++) {
    int nn = n0 + i;
    if (nn >= n) break;
    int g = batch[nn];
    if (g != prev) {
      if (prev >= 0) atomicAdd(&pooled[prev * 64 + d], acc);
      prev = g;
      acc = 0.f;
    }
    acc += h[(size_t)nn * 64 + d];
  }
  if (prev >= 0) atomicAdd(&pooled[prev * 64 + d], acc);
}

// ---------------- output MLP ----------------
__global__ void k_out(const float* __restrict__ pooled, const float* __restrict__ Wo1,
                      const float* __restrict__ bo1, const float* __restrict__ Wo2,
                      const float* __restrict__ bo2, float* __restrict__ out) {
  __shared__ __align__(16) float sP[64 * 64];
  int t = threadIdx.x;
  for (int i = t; i < 1024; i += 256)
    ((float4*)sP)[i] = ((const float4*)pooled)[i];
  __syncthreads();
  int g = t >> 2;
  int q = t & 3;
  float acc = 0.f;
  for (int c = q * 32; c < q * 32 + 32; c++) {
    float t1 = bo1[c];
#pragma unroll 8
    for (int k = 0; k < 64; k++) t1 += sP[g * 64 + k] * Wo1[k * 128 + c];
    acc += fmaxf(t1, 0.f) * Wo2[c];
  }
  acc += __shfl_xor(acc, 1);
  acc += __shfl_xor(acc, 2);
  if (q == 0) out[g] = acc + bo2[0];
}

// ---------------- launch ----------------

static inline char* align_up(char* p, size_t a) {
  return (char*)(((uintptr_t)p + a - 1) & ~(uintptr_t)(a - 1));
}

extern "C" void kernel_launch(void* const* d_in, const int* in_sizes, int n_in,
                              void* d_out, int out_size, void* d_ws, size_t ws_size,
                              hipStream_t stream) {
  const float* x    = (const float*)d_in[0];
  const float* W_in = (const float*)d_in[1];
  const float* b_in = (const float*)d_in[2];
  const float* eps  = (const float*)d_in[3];
  const float* W1   = (const float*)d_in[4];
  const float* b1   = (const float*)d_in[5];
  const float* gam  = (const float*)d_in[6];
  const float* bet  = (const float*)d_in[7];
  const float* W2   = (const float*)d_in[8];
  const float* b2   = (const float*)d_in[9];
  const float* Wo1  = (const float*)d_in[10];
  const float* bo1  = (const float*)d_in[11];
  const float* Wo2  = (const float*)d_in[12];
  const float* bo2  = (const float*)d_in[13];
  const int* ei     = (const int*)d_in[14];
  const int* batch  = (const int*)d_in[15];
  float* out = (float*)d_out;

  const int* e_src = ei;
  const int* e_dst = ei + NE;

  char* p = (char*)d_ws;
  float* h = (float*)p;                     p += (size_t)NN * 64 * 4;   // 25.6 MB
  unsigned short* rh0 = (unsigned short*)p; p += (size_t)NN * 64 * 2;   // 12.8 MB
  unsigned short* rh1 = (unsigned short*)p;
  unsigned int* tmp = (unsigned int*)p;     // tmp aliases rh1 (dead before layer 0)
                                            p += (size_t)NN * 64 * 2;   // 12.8 MB
  int* csr = (int*)p;
  int* hist = (int*)p;                      // hist aliases csr (dead before fillB2)
                                            p += (size_t)NE * 4;        // 6.4 MB
  int* offs = (int*)p;                      p += (size_t)NN * 4;
  int* cnt = (int*)p;                       p += (size_t)NN * 4;
  int* bsumH = (int*)p;                     p += 1280 * 4;
  int* bbase = (int*)p;                     p += (NBUCKET + 1) * 4;
  p = align_up(p, 256);
  float* pooled = (float*)p;                p += (size_t)NGRAPH * 64 * 4;
  p = align_up(p, 256);
  unsigned short* W1t = (unsigned short*)p; p += (size_t)NLAYERS * 8192 * 2;
  unsigned short* W2t = (unsigned short*)p; p += (size_t)NLAYERS * 8192 * 2;
  unsigned short* Wint = (unsigned short*)p; p += 4096 * 2;

  const int SCAN_BLOCKS_H = (NTOT + 255) / 256;      // 1195
  const int NODE_BLOCKS = (NN + 63) / 64;            // 1563

  hipMemsetAsync(pooled, 0, (size_t)NGRAPH * 64 * 4, stream);

  // bucket-level counting sort (atomic-free reservation); per-node offsets
  // derived inside fillB2 — no global k_count / node scan needed.
  k_hist<<<NCHUNK, 256, 0, stream>>>(e_dst, hist);
  k_scan1<<<SCAN_BLOCKS_H, 256, 0, stream>>>(hist, hist, bsumH, NTOT);
  k_scan2b<<<1, 256, 0, stream>>>(bsumH, SCAN_BLOCKS_H);
  k_scan3b<<<SCAN_BLOCKS_H, 256, 0, stream>>>(hist, bsumH, bbase, NTOT);
  k_scatter<<<NCHUNK, 256, 0, stream>>>(e_src, e_dst, hist, tmp);
  k_fillB2<<<NBUCKET, 256, 0, stream>>>(tmp, bbase, csr, offs, cnt);

  k_prep<<<NLAYERS * 2 + 1, 256, 0, stream>>>(W1, W2, W_in, W1t, W2t, Wint);
  k_lin<<<NODE_BLOCKS, 256, 0, stream>>>(x, Wint, b_in, h, rh0);

  for (int l = 0; l < NLAYERS; l++) {
    unsigned short* rin  = (l & 1) ? rh1 : rh0;
    unsigned short* rout = (l & 1) ? rh0 : rh1;
    k_fused<<<NODE_BLOCKS, 256, 0, stream>>>(h, rin, rout, csr, offs, cnt,
        W1t + (size_t)l * 8192, b1 + (size_t)l * 128,
        gam + (size_t)l * 128, bet + (size_t)l * 128,
        W2t + (size_t)l * 8192, b2 + (size_t)l * 64,
        eps + l);
  }

  k_pool<<<(NN + 255) / 256, 256, 0, stream>>>(h, batch, pooled, NN);
  k_out<<<1, 256, 0, stream>>>(pooled, Wo1, bo1, Wo2, bo2, out);
}

// Round 6
// 404.876 us; speedup vs baseline: 2.7531x; 1.0861x over previous
//
#include <hip/hip_runtime.h>
#include <hip/hip_bf16.h>

#define NN 100000
#define NE 1600000
#define DD 64
#define HH 128
#define NLAYERS 4
#define NGRAPH 64
#define NBUCKET 782        // ceil(NN/128) buckets of 128 dst nodes
#define NCHUNK 391         // ceil(NE/4096) edge chunks of 4096
#define NTOT (NBUCKET * NCHUNK)

typedef __attribute__((ext_vector_type(8))) short bf16x8;
typedef __attribute__((ext_vector_type(4))) float f32x4;

__device__ inline unsigned short bf16bits(float v) {
  return __bfloat16_as_ushort(__float2bfloat16(v));
}

// ---------------- CSR build ----------------

__global__ void k_hist(const int* __restrict__ dst, int* __restrict__ hist) {
  __shared__ int lh[NBUCKET];
  int t = threadIdx.x;
  int blk = blockIdx.x;
  for (int i = t; i < NBUCKET; i += 256) lh[i] = 0;
  __syncthreads();
  int cb = blk * 4096;
  int end = min(cb + 4096, NE);
  for (int i = cb + t; i < end; i += 256)
    atomicAdd(&lh[dst[i] >> 7], 1);
  __syncthreads();
  for (int i = t; i < NBUCKET; i += 256)
    hist[i * NCHUNK + blk] = lh[i];
}

__global__ void k_scan1(const int* __restrict__ in, int* __restrict__ out,
                        int* __restrict__ bsum, int n) {
  __shared__ int s[256];
  int t = threadIdx.x;
  int i = blockIdx.x * 256 + t;
  int v = (i < n) ? in[i] : 0;
  s[t] = v;
  __syncthreads();
  for (int off = 1; off < 256; off <<= 1) {
    int x = (t >= off) ? s[t - off] : 0;
    __syncthreads();
    s[t] += x;
    __syncthreads();
  }
  if (i < n) out[i] = s[t] - v;
  if (t == 255) bsum[blockIdx.x] = s[255];
}

__global__ void k_scan2b(int* bsum, int nb) {
  __shared__ int s[256];
  int t = threadIdx.x;
  int base = t * 5;
  int v[5];
  int sum = 0;
#pragma unroll
  for (int j = 0; j < 5; j++) {
    int i = base + j;
    v[j] = (i < nb) ? bsum[i] : 0;
    sum += v[j];
  }
  s[t] = sum;
  __syncthreads();
  for (int off = 1; off < 256; off <<= 1) {
    int x = (t >= off) ? s[t - off] : 0;
    __syncthreads();
    s[t] += x;
    __syncthreads();
  }
  int ex = s[t] - sum;
#pragma unroll
  for (int j = 0; j < 5; j++) {
    int i = base + j;
    if (i < nb) { int vv = v[j]; bsum[i] = ex; ex += vv; }
  }
}

// finalize hist offsets + extract per-bucket bases (avoids hist/csr alias race)
__global__ void k_scan3b(int* __restrict__ hist, const int* __restrict__ bsum,
                         int* __restrict__ bbase, int n) {
  int i = blockIdx.x * 256 + threadIdx.x;
  if (i < n) {
    int v = hist[i] + bsum[i >> 8];
    hist[i] = v;
    if (i % NCHUNK == 0) bbase[i / NCHUNK] = v;
  }
}

__global__ void k_scatter(const int* __restrict__ src, const int* __restrict__ dst,
                          const int* __restrict__ hist, unsigned int* __restrict__ tmp) {
  __shared__ int lcur[NBUCKET];
  int t = threadIdx.x;
  int blk = blockIdx.x;
  for (int i = t; i < NBUCKET; i += 256) lcur[i] = hist[i * NCHUNK + blk];
  __syncthreads();
  int cb = blk * 4096;
  int end = min(cb + 4096, NE);
  for (int i = cb + t; i < end; i += 256) {
    int d = dst[i];
    int pos = atomicAdd(&lcur[d >> 7], 1);
    tmp[pos] = ((unsigned int)(d & 127) << 20) | (unsigned int)src[i];
  }
}

// per-bucket: derive per-node offs/cnt (LDS count+scan), then place edges
__global__ void k_fillB2(const unsigned int* __restrict__ tmp,
                         const int* __restrict__ bbase,
                         int* __restrict__ csr, int* __restrict__ offs,
                         int* __restrict__ cnt) {
  __shared__ int lcnt[128], lex[128], lcur[128];
  int b = blockIdx.x;
  int t = threadIdx.x;
  int base = bbase[b];
  int end = (b == NBUCKET - 1) ? NE : bbase[b + 1];
  if (t < 128) lcnt[t] = 0;
  __syncthreads();
  for (int i = base + t; i < end; i += 256)
    atomicAdd(&lcnt[tmp[i] >> 20], 1);
  __syncthreads();
  int v = (t < 128) ? lcnt[t] : 0;
  if (t < 128) lex[t] = v;
  __syncthreads();
  for (int off = 1; off < 128; off <<= 1) {
    int x = (t >= off && t < 128) ? lex[t - off] : 0;
    __syncthreads();
    if (t < 128) lex[t] += x;
    __syncthreads();
  }
  if (t < 128) {
    int ex = lex[t] - v;
    lcur[t] = ex;
    int node = (b << 7) + t;
    if (node < NN) { offs[node] = base + ex; cnt[node] = v; }
  }
  __syncthreads();
  for (int i = base + t; i < end; i += 256) {
    unsigned int u = tmp[i];
    int dl = u >> 20;
    int pos = atomicAdd(&lcur[dl], 1);
    csr[base + pos] = u & 0xFFFFF;
  }
}

// ---------------- weight prep: bf16 transposed copies ----------------
__global__ void k_prep(const float* __restrict__ W1, const float* __restrict__ W2,
                       const float* __restrict__ W_in,
                       unsigned short* __restrict__ W1t, unsigned short* __restrict__ W2t,
                       unsigned short* __restrict__ Wint) {
  int bidx = blockIdx.x;
  int t = threadIdx.x;
  if (bidx == 2 * NLAYERS) {
    for (int i = t; i < 4096; i += 256) {
      int c = i >> 6, k = i & 63;
      Wint[i] = bf16bits(W_in[k * 64 + c]);
    }
    return;
  }
  int l = bidx >> 1;
  int m = bidx & 1;
  if (m == 0) {
    const float* src = W1 + (size_t)l * 8192;
    unsigned short* dstp = W1t + (size_t)l * 8192;
    for (int i = t; i < 8192; i += 256) {
      int c = i >> 6, k = i & 63;
      dstp[i] = bf16bits(src[k * 128 + c]);
    }
  } else {
    const float* src = W2 + (size_t)l * 8192;
    unsigned short* dstp = W2t + (size_t)l * 8192;
    for (int i = t; i < 8192; i += 256) {
      int c = i >> 7, k = i & 127;
      dstp[i] = bf16bits(src[k * 64 + c]);
    }
  }
}

// ---------------- lin_in via MFMA: h = x @ W_in + b_in ; rh = bf16(relu(h)) -------
__global__ __launch_bounds__(256) void k_lin(
    const float* __restrict__ x, const unsigned short* __restrict__ Wint,
    const float* __restrict__ binp, float* __restrict__ h,
    unsigned short* __restrict__ rh) {
  __shared__ __align__(16) unsigned short sW[4096];   // [c=64][8 slots swz]
  __shared__ float sb[64];
  int t = threadIdx.x;
  {
    const uint4* wg = (const uint4*)Wint;
    uint4* sWu = (uint4*)sW;
    for (int g = t; g < 512; g += 256) {
      int c = g >> 3, s = g & 7;
      sWu[c * 8 + (s ^ (c & 7))] = wg[g];
    }
    if (t < 64) sb[t] = binp[t];
  }
  int l = t & 63, w = t >> 6, lm = l & 15, lk = l >> 4;
  int rowl = w * 16 + lm;
  int grow = blockIdx.x * 64 + rowl;
  int growc = min(grow, NN - 1);
  bf16x8 a[2];
#pragma unroll
  for (int kb = 0; kb < 2; kb++) {
    const float* xp = &x[(size_t)growc * 64 + kb * 32 + lk * 8];
    float4 x0 = *(const float4*)xp;
    float4 x1 = *(const float4*)(xp + 4);
    a[kb][0] = (short)bf16bits(x0.x); a[kb][1] = (short)bf16bits(x0.y);
    a[kb][2] = (short)bf16bits(x0.z); a[kb][3] = (short)bf16bits(x0.w);
    a[kb][4] = (short)bf16bits(x1.x); a[kb][5] = (short)bf16bits(x1.y);
    a[kb][6] = (short)bf16bits(x1.z); a[kb][7] = (short)bf16bits(x1.w);
  }
  __syncthreads();
  f32x4 acc[4];
#pragma unroll
  for (int n = 0; n < 4; n++) {
    float bc = sb[n * 16 + lm];
    acc[n] = (f32x4){bc, bc, bc, bc};
  }
  const bf16x8* sWf = (const bf16x8*)sW;
#pragma unroll
  for (int n = 0; n < 4; n++) {
    int c = n * 16 + lm;
    bf16x8 b0 = sWf[c * 8 + ((0 * 4 + lk) ^ (c & 7))];
    bf16x8 b1 = sWf[c * 8 + ((1 * 4 + lk) ^ (c & 7))];
    acc[n] = __builtin_amdgcn_mfma_f32_16x16x32_bf16(a[0], b0, acc[n], 0, 0, 0);
    acc[n] = __builtin_amdgcn_mfma_f32_16x16x32_bf16(a[1], b1, acc[n], 0, 0, 0);
  }
#pragma unroll
  for (int r = 0; r < 4; r++) {
    int grow2 = blockIdx.x * 64 + w * 16 + lk * 4 + r;
    if (grow2 < NN) {
#pragma unroll
      for (int n = 0; n < 4; n++) {
        int c = n * 16 + lm;
        size_t idx = (size_t)grow2 * 64 + c;
        float o = acc[n][r];
        h[idx] = o;
        rh[idx] = bf16bits(fmaxf(o, 0.f));
      }
    }
  }
}

// ---------------- fused layer: gather + MLP (MFMA) ----------------
// 64 nodes/block, 4 waves. Batched gather (4 edges' loads in flight);
// z = (1+eps)*h + agg -> A-frags; GEMM1 (sW=W1); LN+relu -> sRr;
// restage sW=W2; GEMM2; h += out; rhout = bf16(relu(h)).
// LDS ~33.8 KB -> 4 blocks/CU.
__global__ __launch_bounds__(256) void k_fused(
    float* __restrict__ h, const unsigned short* __restrict__ rhin,
    unsigned short* __restrict__ rhout,
    const int* __restrict__ csr, const int* __restrict__ offs,
    const int* __restrict__ cnt,
    const unsigned short* __restrict__ W1t, const float* __restrict__ b1l,
    const float* __restrict__ gl, const float* __restrict__ btl,
    const unsigned short* __restrict__ W2t, const float* __restrict__ b2l,
    const float* __restrict__ epsl) {
  __shared__ __align__(16) unsigned short sW[8192];   // W1 [c=128][8 swz] then W2 [c=64][16 swz]
  __shared__ __align__(16) unsigned short sRr[8192];  // [r=64][16 slots swz]
  __shared__ float sb1[128], sg[128], sbt[128], sb2[64];

  int t = threadIdx.x;
  int nbase = blockIdx.x * 64;
  int l = t & 63;
  int w = t >> 6;
  int lm = l & 15;
  int lk = l >> 4;

  // stage W1 (swizzled 16B slots) + params
  {
    const uint4* w1g = (const uint4*)W1t;
    uint4* sWu = (uint4*)sW;
    for (int g = t; g < 1024; g += 256) {
      int c = g >> 3, s = g & 7;
      sWu[c * 8 + (s ^ (c & 7))] = w1g[g];
    }
    if (t < 128) { sb1[t] = b1l[t]; sg[t] = gl[t]; sbt[t] = btl[t]; }
    if (t < 64) sb2[t] = b2l[t];
  }
  float epsv = 1.0f + *epsl;

  // ---- gather phase: 4 threads/node, 16 dims each; 4 edges batched ----
  int rowl = w * 16 + lm;
  int grow = nbase + rowl;
  int growc = min(grow, NN - 1);
  int start = offs[growc];
  int deg = (grow < NN) ? cnt[growc] : 0;
  float accA[8] = {0.f, 0.f, 0.f, 0.f, 0.f, 0.f, 0.f, 0.f};
  float accB[8] = {0.f, 0.f, 0.f, 0.f, 0.f, 0.f, 0.f, 0.f};
  for (int j0 = 0; j0 < deg; j0 += 4) {
    int myj = j0 + lk;
    int idx = (myj < deg) ? csr[start + myj] : 0;
    int c4 = deg - j0;
    int ss[4];
#pragma unroll
    for (int jj = 0; jj < 4; jj++) ss[jj] = __shfl(idx, lm + jj * 16);
    uint4 va[4], vb[4];
#pragma unroll
    for (int jj = 0; jj < 4; jj++) {
      const unsigned short* rp = rhin + (size_t)ss[jj] * 64 + lk * 8;
      va[jj] = *(const uint4*)rp;
      vb[jj] = *(const uint4*)(rp + 32);
    }
#pragma unroll
    for (int jj = 0; jj < 4; jj++) {
      if (jj < c4) {
        uint4 vA = va[jj], vB = vb[jj];
        accA[0] += __uint_as_float(vA.x << 16);
        accA[1] += __uint_as_float(vA.x & 0xFFFF0000u);
        accA[2] += __uint_as_float(vA.y << 16);
        accA[3] += __uint_as_float(vA.y & 0xFFFF0000u);
        accA[4] += __uint_as_float(vA.z << 16);
        accA[5] += __uint_as_float(vA.z & 0xFFFF0000u);
        accA[6] += __uint_as_float(vA.w << 16);
        accA[7] += __uint_as_float(vA.w & 0xFFFF0000u);
        accB[0] += __uint_as_float(vB.x << 16);
        accB[1] += __uint_as_float(vB.x & 0xFFFF0000u);
        accB[2] += __uint_as_float(vB.y << 16);
        accB[3] += __uint_as_float(vB.y & 0xFFFF0000u);
        accB[4] += __uint_as_float(vB.z << 16);
        accB[5] += __uint_as_float(vB.z & 0xFFFF0000u);
        accB[6] += __uint_as_float(vB.w << 16);
        accB[7] += __uint_as_float(vB.w & 0xFFFF0000u);
      }
    }
  }

  // z = (1+eps)*h + agg -> A-frags
  bf16x8 a1[2];
  {
    const float* hp = &h[(size_t)growc * 64 + lk * 8];
#pragma unroll
    for (int j = 0; j < 8; j++)
      a1[0][j] = (short)bf16bits(epsv * hp[j] + accA[j]);
    const float* hp2 = hp + 32;
#pragma unroll
    for (int j = 0; j < 8; j++)
      a1[1][j] = (short)bf16bits(epsv * hp2[j] + accB[j]);
  }
  __syncthreads();

  // GEMM1: acc1[n] over 8 col-tiles (sW holds W1)
  f32x4 acc1[8];
#pragma unroll
  for (int n = 0; n < 8; n++) {
    float bc = sb1[n * 16 + lm];
    acc1[n] = (f32x4){bc, bc, bc, bc};
  }
  {
    const bf16x8* sW1f = (const bf16x8*)sW;
#pragma unroll
    for (int n = 0; n < 8; n++) {
      int c = n * 16 + lm;
      bf16x8 b0 = sW1f[c * 8 + ((0 * 4 + lk) ^ (c & 7))];
      bf16x8 b1f = sW1f[c * 8 + ((1 * 4 + lk) ^ (c & 7))];
      acc1[n] = __builtin_amdgcn_mfma_f32_16x16x32_bf16(a1[0], b0, acc1[n], 0, 0, 0);
      acc1[n] = __builtin_amdgcn_mfma_f32_16x16x32_bf16(a1[1], b1f, acc1[n], 0, 0, 0);
    }
  }

  // LayerNorm + relu on D-frags, write swizzled sRr
  float psr[4], pqr[4];
#pragma unroll
  for (int r = 0; r < 4; r++) {
    float s = 0.f, q = 0.f;
#pragma unroll
    for (int n = 0; n < 8; n++) { float v = acc1[n][r]; s += v; q += v * v; }
    psr[r] = s; pqr[r] = q;
  }
#pragma unroll
  for (int m = 1; m <= 8; m <<= 1) {
#pragma unroll
    for (int r = 0; r < 4; r++) {
      psr[r] += __shfl_xor(psr[r], m);
      pqr[r] += __shfl_xor(pqr[r], m);
    }
  }
#pragma unroll
  for (int r = 0; r < 4; r++) {
    float mu = psr[r] * (1.0f / 128.0f);
    float var = pqr[r] * (1.0f / 128.0f) - mu * mu;
    float rs = rsqrtf(var + 1e-5f);
    int rowr = w * 16 + lk * 4 + r;
#pragma unroll
    for (int n = 0; n < 8; n++) {
      int c = n * 16 + lm;
      float v = (acc1[n][r] - mu) * rs * sg[c] + sbt[c];
      v = fmaxf(v, 0.f);
      int slot = (c >> 3) ^ (rowr & 7);
      sRr[rowr * 128 + slot * 8 + (c & 7)] = bf16bits(v);
    }
  }
  __syncthreads();   // sRr ready; all waves past GEMM1 -> sW reusable

  // restage sW = W2 (L2-resident; swizzled 16B slots)
  {
    const uint4* w2g = (const uint4*)W2t;
    uint4* sWu = (uint4*)sW;
    for (int g = t; g < 1024; g += 256) {
      int c = g >> 4, s = g & 15;
      sWu[c * 16 + (s ^ (c & 15))] = w2g[g];
    }
  }
  __syncthreads();   // sW2 ready

  // GEMM2
  f32x4 acc2[4];
#pragma unroll
  for (int n2 = 0; n2 < 4; n2++) {
    float bc = sb2[n2 * 16 + lm];
    acc2[n2] = (f32x4){bc, bc, bc, bc};
  }
  {
    const bf16x8* sRf = (const bf16x8*)sRr;
    const bf16x8* sW2f = (const bf16x8*)sW;
    bf16x8 a2[4];
#pragma unroll
    for (int kb = 0; kb < 4; kb++)
      a2[kb] = sRf[rowl * 16 + ((kb * 4 + lk) ^ (rowl & 7))];
#pragma unroll
    for (int n2 = 0; n2 < 4; n2++) {
      int c = n2 * 16 + lm;
#pragma unroll
      for (int kb = 0; kb < 4; kb++) {
        bf16x8 bfr = sW2f[c * 16 + ((kb * 4 + lk) ^ (c & 15))];
        acc2[n2] = __builtin_amdgcn_mfma_f32_16x16x32_bf16(a2[kb], bfr, acc2[n2], 0, 0, 0);
      }
    }
  }

  // epilogue: h += out + b2 ; rhout = bf16(relu(h))
#pragma unroll
  for (int r = 0; r < 4; r++) {
    int grow2 = nbase + w * 16 + lk * 4 + r;
    if (grow2 < NN) {
#pragma unroll
      for (int n2 = 0; n2 < 4; n2++) {
        int c = n2 * 16 + lm;
        size_t idx = (size_t)grow2 * 64 + c;
        float o = h[idx] + acc2[n2][r];
        h[idx] = o;
        rhout[idx] = bf16bits(fmaxf(o, 0.f));
      }
    }
  }
}

// ---------------- pooling ----------------
__global__ void k_pool(const float* __restrict__ h, const int* __restrict__ batch,
                       float* __restrict__ pooled, int n) {
  int t = threadIdx.x;
  int d = t & 63;
  int w = t >> 6;
  int n0 = blockIdx.x * 256 + w * 64;
  float acc = 0.f;
  int prev = -1;
  for (int i = 0; i < 64; i++) {
    int nn = n0 + i;
    if (nn >= n) break;
    int g = batch[nn];
    if (g != prev) {
      if (prev >= 0) atomicAdd(&pooled[prev * 64 + d], acc);
      prev = g;
      acc = 0.f;
    }
    acc += h[(size_t)nn * 64 + d];
  }
  if (prev >= 0) atomicAdd(&pooled[prev * 64 + d], acc);
}

// ---------------- output MLP ----------------
__global__ void k_out(const float* __restrict__ pooled, const float* __restrict__ Wo1,
                      const float* __restrict__ bo1, const float* __restrict__ Wo2,
                      const float* __restrict__ bo2, float* __restrict__ out) {
  __shared__ __align__(16) float sP[64 * 64];
  int t = threadIdx.x;
  for (int i = t; i < 1024; i += 256)
    ((float4*)sP)[i] = ((const float4*)pooled)[i];
  __syncthreads();
  int g = t >> 2;
  int q = t & 3;
  float acc = 0.f;
  for (int c = q * 32; c < q * 32 + 32; c++) {
    float t1 = bo1[c];
#pragma unroll 8
    for (int k = 0; k < 64; k++) t1 += sP[g * 64 + k] * Wo1[k * 128 + c];
    acc += fmaxf(t1, 0.f) * Wo2[c];
  }
  acc += __shfl_xor(acc, 1);
  acc += __shfl_xor(acc, 2);
  if (q == 0) out[g] = acc + bo2[0];
}

// ---------------- launch ----------------

static inline char* align_up(char* p, size_t a) {
  return (char*)(((uintptr_t)p + a - 1) & ~(uintptr_t)(a - 1));
}

extern "C" void kernel_launch(void* const* d_in, const int* in_sizes, int n_in,
                              void* d_out, int out_size, void* d_ws, size_t ws_size,
                              hipStream_t stream) {
  const float* x    = (const float*)d_in[0];
  const float* W_in = (const float*)d_in[1];
  const float* b_in = (const float*)d_in[2];
  const float* eps  = (const float*)d_in[3];
  const float* W1   = (const float*)d_in[4];
  const float* b1   = (const float*)d_in[5];
  const float* gam  = (const float*)d_in[6];
  const float* bet  = (const float*)d_in[7];
  const float* W2   = (const float*)d_in[8];
  const float* b2   = (const float*)d_in[9];
  const float* Wo1  = (const float*)d_in[10];
  const float* bo1  = (const float*)d_in[11];
  const float* Wo2  = (const float*)d_in[12];
  const float* bo2  = (const float*)d_in[13];
  const int* ei     = (const int*)d_in[14];
  const int* batch  = (const int*)d_in[15];
  float* out = (float*)d_out;

  const int* e_src = ei;
  const int* e_dst = ei + NE;

  char* p = (char*)d_ws;
  float* h = (float*)p;                     p += (size_t)NN * 64 * 4;   // 25.6 MB
  unsigned short* rh0 = (unsigned short*)p; p += (size_t)NN * 64 * 2;   // 12.8 MB
  unsigned short* rh1 = (unsigned short*)p;
  unsigned int* tmp = (unsigned int*)p;     // tmp aliases rh1 (dead before layer 0)
                                            p += (size_t)NN * 64 * 2;   // 12.8 MB
  int* csr = (int*)p;
  int* hist = (int*)p;                      // hist aliases csr (dead before fillB2)
                                            p += (size_t)NE * 4;        // 6.4 MB
  int* offs = (int*)p;                      p += (size_t)NN * 4;
  int* cnt = (int*)p;                       p += (size_t)NN * 4;
  int* bsumH = (int*)p;                     p += 1280 * 4;
  int* bbase = (int*)p;                     p += (NBUCKET + 1) * 4;
  p = align_up(p, 256);
  float* pooled = (float*)p;                p += (size_t)NGRAPH * 64 * 4;
  p = align_up(p, 256);
  unsigned short* W1t = (unsigned short*)p; p += (size_t)NLAYERS * 8192 * 2;
  unsigned short* W2t = (unsigned short*)p; p += (size_t)NLAYERS * 8192 * 2;
  unsigned short* Wint = (unsigned short*)p; p += 4096 * 2;

  const int SCAN_BLOCKS_H = (NTOT + 255) / 256;      // 1195
  const int NODE_BLOCKS = (NN + 63) / 64;            // 1563

  hipMemsetAsync(pooled, 0, (size_t)NGRAPH * 64 * 4, stream);

  // bucket-level counting sort (atomic-free reservation); per-node offsets
  // derived inside fillB2 — no global k_count / node scan needed.
  k_hist<<<NCHUNK, 256, 0, stream>>>(e_dst, hist);
  k_scan1<<<SCAN_BLOCKS_H, 256, 0, stream>>>(hist, hist, bsumH, NTOT);
  k_scan2b<<<1, 256, 0, stream>>>(bsumH, SCAN_BLOCKS_H);
  k_scan3b<<<SCAN_BLOCKS_H, 256, 0, stream>>>(hist, bsumH, bbase, NTOT);
  k_scatter<<<NCHUNK, 256, 0, stream>>>(e_src, e_dst, hist, tmp);
  k_fillB2<<<NBUCKET, 256, 0, stream>>>(tmp, bbase, csr, offs, cnt);

  k_prep<<<NLAYERS * 2 + 1, 256, 0, stream>>>(W1, W2, W_in, W1t, W2t, Wint);
  k_lin<<<NODE_BLOCKS, 256, 0, stream>>>(x, Wint, b_in, h, rh0);

  for (int l = 0; l < NLAYERS; l++) {
    unsigned short* rin  = (l & 1) ? rh1 : rh0;
    unsigned short* rout = (l & 1) ? rh0 : rh1;
    k_fused<<<NODE_BLOCKS, 256, 0, stream>>>(h, rin, rout, csr, offs, cnt,
        W1t + (size_t)l * 8192, b1 + (size_t)l * 128,
        gam + (size_t)l * 128, bet + (size_t)l * 128,
        W2t + (size_t)l * 8192, b2 + (size_t)l * 64,
        eps + l);
  }

  k_pool<<<(NN + 255) / 256, 256, 0, stream>>>(h, batch, pooled, NN);
  k_out<<<1, 256, 0, stream>>>(pooled, Wo1, bo1, Wo2, bo2, out);
}

// Round 7
// 347.452 us; speedup vs baseline: 3.2081x; 1.1653x over previous
//
#include <hip/hip_runtime.h>
#include <hip/hip_bf16.h>

#define NN 100000
#define NE 1600000
#define DD 64
#define HH 128
#define NLAYERS 4
#define NGRAPH 64
#define NBUCKET 782        // ceil(NN/128) buckets of 128 dst nodes
#define NCHUNK 391         // ceil(NE/4096) edge chunks of 4096
#define NTOT (NBUCKET * NCHUNK)

typedef __attribute__((ext_vector_type(8))) short bf16x8;
typedef __attribute__((ext_vector_type(4))) float f32x4;

__device__ inline unsigned short bf16bits(float v) {
  return __bfloat16_as_ushort(__float2bfloat16(v));
}

// ---------------- CSR build ----------------

__global__ void k_hist(const int* __restrict__ dst, int* __restrict__ hist) {
  __shared__ int lh[NBUCKET];
  int t = threadIdx.x;
  int blk = blockIdx.x;
  for (int i = t; i < NBUCKET; i += 256) lh[i] = 0;
  __syncthreads();
  int cb = blk * 4096;
  int end = min(cb + 4096, NE);
  for (int i = cb + t; i < end; i += 256)
    atomicAdd(&lh[dst[i] >> 7], 1);
  __syncthreads();
  for (int i = t; i < NBUCKET; i += 256)
    hist[i * NCHUNK + blk] = lh[i];
}

__global__ void k_scan1(const int* __restrict__ in, int* __restrict__ out,
                        int* __restrict__ bsum, int n) {
  __shared__ int s[256];
  int t = threadIdx.x;
  int i = blockIdx.x * 256 + t;
  int v = (i < n) ? in[i] : 0;
  s[t] = v;
  __syncthreads();
  for (int off = 1; off < 256; off <<= 1) {
    int x = (t >= off) ? s[t - off] : 0;
    __syncthreads();
    s[t] += x;
    __syncthreads();
  }
  if (i < n) out[i] = s[t] - v;
  if (t == 255) bsum[blockIdx.x] = s[255];
}

__global__ void k_scan2b(int* bsum, int nb) {
  __shared__ int s[256];
  int t = threadIdx.x;
  int base = t * 5;
  int v[5];
  int sum = 0;
#pragma unroll
  for (int j = 0; j < 5; j++) {
    int i = base + j;
    v[j] = (i < nb) ? bsum[i] : 0;
    sum += v[j];
  }
  s[t] = sum;
  __syncthreads();
  for (int off = 1; off < 256; off <<= 1) {
    int x = (t >= off) ? s[t - off] : 0;
    __syncthreads();
    s[t] += x;
    __syncthreads();
  }
  int ex = s[t] - sum;
#pragma unroll
  for (int j = 0; j < 5; j++) {
    int i = base + j;
    if (i < nb) { int vv = v[j]; bsum[i] = ex; ex += vv; }
  }
}

// finalize hist offsets + extract per-bucket bases (avoids hist/csr alias race)
__global__ void k_scan3b(int* __restrict__ hist, const int* __restrict__ bsum,
                         int* __restrict__ bbase, int n) {
  int i = blockIdx.x * 256 + threadIdx.x;
  if (i < n) {
    int v = hist[i] + bsum[i >> 8];
    hist[i] = v;
    if (i % NCHUNK == 0) bbase[i / NCHUNK] = v;
  }
}

__global__ void k_scatter(const int* __restrict__ src, const int* __restrict__ dst,
                          const int* __restrict__ hist, unsigned int* __restrict__ tmp) {
  __shared__ int lcur[NBUCKET];
  int t = threadIdx.x;
  int blk = blockIdx.x;
  for (int i = t; i < NBUCKET; i += 256) lcur[i] = hist[i * NCHUNK + blk];
  __syncthreads();
  int cb = blk * 4096;
  int end = min(cb + 4096, NE);
  for (int i = cb + t; i < end; i += 256) {
    int d = dst[i];
    int pos = atomicAdd(&lcur[d >> 7], 1);
    tmp[pos] = ((unsigned int)(d & 127) << 20) | (unsigned int)src[i];
  }
}

// per-bucket: derive per-node offs/cnt (LDS count+scan), then place edges
__global__ void k_fillB2(const unsigned int* __restrict__ tmp,
                         const int* __restrict__ bbase,
                         int* __restrict__ csr, int* __restrict__ offs,
                         int* __restrict__ cnt) {
  __shared__ int lcnt[128], lex[128], lcur[128];
  int b = blockIdx.x;
  int t = threadIdx.x;
  int base = bbase[b];
  int end = (b == NBUCKET - 1) ? NE : bbase[b + 1];
  if (t < 128) lcnt[t] = 0;
  __syncthreads();
  for (int i = base + t; i < end; i += 256)
    atomicAdd(&lcnt[tmp[i] >> 20], 1);
  __syncthreads();
  int v = (t < 128) ? lcnt[t] : 0;
  if (t < 128) lex[t] = v;
  __syncthreads();
  for (int off = 1; off < 128; off <<= 1) {
    int x = (t >= off && t < 128) ? lex[t - off] : 0;
    __syncthreads();
    if (t < 128) lex[t] += x;
    __syncthreads();
  }
  if (t < 128) {
    int ex = lex[t] - v;
    lcur[t] = ex;
    int node = (b << 7) + t;
    if (node < NN) { offs[node] = base + ex; cnt[node] = v; }
  }
  __syncthreads();
  for (int i = base + t; i < end; i += 256) {
    unsigned int u = tmp[i];
    int dl = u >> 20;
    int pos = atomicAdd(&lcur[dl], 1);
    csr[base + pos] = u & 0xFFFFF;
  }
}

// ---------------- weight prep: bf16 transposed copies ----------------
__global__ void k_prep(const float* __restrict__ W1, const float* __restrict__ W2,
                       const float* __restrict__ W_in,
                       unsigned short* __restrict__ W1t, unsigned short* __restrict__ W2t,
                       unsigned short* __restrict__ Wint) {
  int bidx = blockIdx.x;
  int t = threadIdx.x;
  if (bidx == 2 * NLAYERS) {
    for (int i = t; i < 4096; i += 256) {
      int c = i >> 6, k = i & 63;
      Wint[i] = bf16bits(W_in[k * 64 + c]);
    }
    return;
  }
  int l = bidx >> 1;
  int m = bidx & 1;
  if (m == 0) {
    const float* src = W1 + (size_t)l * 8192;
    unsigned short* dstp = W1t + (size_t)l * 8192;
    for (int i = t; i < 8192; i += 256) {
      int c = i >> 6, k = i & 63;
      dstp[i] = bf16bits(src[k * 128 + c]);
    }
  } else {
    const float* src = W2 + (size_t)l * 8192;
    unsigned short* dstp = W2t + (size_t)l * 8192;
    for (int i = t; i < 8192; i += 256) {
      int c = i >> 7, k = i & 127;
      dstp[i] = bf16bits(src[k * 64 + c]);
    }
  }
}

// ---------------- lin_in via MFMA: h = x @ W_in + b_in ; rh = bf16(relu(h)) -------
__global__ __launch_bounds__(256) void k_lin(
    const float* __restrict__ x, const unsigned short* __restrict__ Wint,
    const float* __restrict__ binp, float* __restrict__ h,
    unsigned short* __restrict__ rh) {
  __shared__ __align__(16) unsigned short sW[4096];   // [c=64][8 slots swz]
  __shared__ float sb[64];
  int t = threadIdx.x;
  {
    const uint4* wg = (const uint4*)Wint;
    uint4* sWu = (uint4*)sW;
    for (int g = t; g < 512; g += 256) {
      int c = g >> 3, s = g & 7;
      sWu[c * 8 + (s ^ (c & 7))] = wg[g];
    }
    if (t < 64) sb[t] = binp[t];
  }
  int l = t & 63, w = t >> 6, lm = l & 15, lk = l >> 4;
  int rowl = w * 16 + lm;
  int grow = blockIdx.x * 64 + rowl;
  int growc = min(grow, NN - 1);
  bf16x8 a[2];
#pragma unroll
  for (int kb = 0; kb < 2; kb++) {
    const float* xp = &x[(size_t)growc * 64 + kb * 32 + lk * 8];
    float4 x0 = *(const float4*)xp;
    float4 x1 = *(const float4*)(xp + 4);
    a[kb][0] = (short)bf16bits(x0.x); a[kb][1] = (short)bf16bits(x0.y);
    a[kb][2] = (short)bf16bits(x0.z); a[kb][3] = (short)bf16bits(x0.w);
    a[kb][4] = (short)bf16bits(x1.x); a[kb][5] = (short)bf16bits(x1.y);
    a[kb][6] = (short)bf16bits(x1.z); a[kb][7] = (short)bf16bits(x1.w);
  }
  __syncthreads();
  f32x4 acc[4];
#pragma unroll
  for (int n = 0; n < 4; n++) {
    float bc = sb[n * 16 + lm];
    acc[n] = (f32x4){bc, bc, bc, bc};
  }
  const bf16x8* sWf = (const bf16x8*)sW;
#pragma unroll
  for (int n = 0; n < 4; n++) {
    int c = n * 16 + lm;
    bf16x8 b0 = sWf[c * 8 + ((0 * 4 + lk) ^ (c & 7))];
    bf16x8 b1 = sWf[c * 8 + ((1 * 4 + lk) ^ (c & 7))];
    acc[n] = __builtin_amdgcn_mfma_f32_16x16x32_bf16(a[0], b0, acc[n], 0, 0, 0);
    acc[n] = __builtin_amdgcn_mfma_f32_16x16x32_bf16(a[1], b1, acc[n], 0, 0, 0);
  }
#pragma unroll
  for (int r = 0; r < 4; r++) {
    int grow2 = blockIdx.x * 64 + w * 16 + lk * 4 + r;
    if (grow2 < NN) {
#pragma unroll
      for (int n = 0; n < 4; n++) {
        int c = n * 16 + lm;
        size_t idx = (size_t)grow2 * 64 + c;
        float o = acc[n][r];
        h[idx] = o;
        rh[idx] = bf16bits(fmaxf(o, 0.f));
      }
    }
  }
}

// ---------------- fused layer: gather + MLP (MFMA) ----------------
// 64 nodes/block, 4 waves. 8-edge-batched gather (16 loads in flight/thread);
// early h prefetch; GEMM1 (sW=W1); LN+relu -> sRr; restage sW=W2; GEMM2;
// h += out; rhout = bf16(relu(h)). LDS ~33.8 KB -> 4 blocks/CU.
__global__ __launch_bounds__(256) void k_fused(
    float* __restrict__ h, const unsigned short* __restrict__ rhin,
    unsigned short* __restrict__ rhout,
    const int* __restrict__ csr, const int* __restrict__ offs,
    const int* __restrict__ cnt,
    const unsigned short* __restrict__ W1t, const float* __restrict__ b1l,
    const float* __restrict__ gl, const float* __restrict__ btl,
    const unsigned short* __restrict__ W2t, const float* __restrict__ b2l,
    const float* __restrict__ epsl) {
  __shared__ __align__(16) unsigned short sW[8192];   // W1 [c=128][8 swz] then W2 [c=64][16 swz]
  __shared__ __align__(16) unsigned short sRr[8192];  // [r=64][16 slots swz]
  __shared__ float sb1[128], sg[128], sbt[128], sb2[64];

  int t = threadIdx.x;
  int nbase = blockIdx.x * 64;
  int l = t & 63;
  int w = t >> 6;
  int lm = l & 15;
  int lk = l >> 4;

  // stage W1 (swizzled 16B slots) + params
  {
    const uint4* w1g = (const uint4*)W1t;
    uint4* sWu = (uint4*)sW;
    for (int g = t; g < 1024; g += 256) {
      int c = g >> 3, s = g & 7;
      sWu[c * 8 + (s ^ (c & 7))] = w1g[g];
    }
    if (t < 128) { sb1[t] = b1l[t]; sg[t] = gl[t]; sbt[t] = btl[t]; }
    if (t < 64) sb2[t] = b2l[t];
  }
  float epsv = 1.0f + *epsl;

  int rowl = w * 16 + lm;
  int grow = nbase + rowl;
  int growc = min(grow, NN - 1);
  int start = offs[growc];
  int deg = (grow < NN) ? cnt[growc] : 0;

  // issue-early: residual h loads (consumed after the gather loop)
  const float* hp = &h[(size_t)growc * 64 + lk * 8];
  float4 hv0 = *(const float4*)hp;
  float4 hv1 = *(const float4*)(hp + 4);
  float4 hv2 = *(const float4*)(hp + 32);
  float4 hv3 = *(const float4*)(hp + 36);

  // ---- gather: 4 threads/node, 16 dims each; 8 edges batched ----
  float accA[8] = {0.f, 0.f, 0.f, 0.f, 0.f, 0.f, 0.f, 0.f};
  float accB[8] = {0.f, 0.f, 0.f, 0.f, 0.f, 0.f, 0.f, 0.f};
  for (int j0 = 0; j0 < deg; j0 += 8) {
    int idxA = csr[start + j0 + lk];        // may over-read within d_ws; guarded below
    int idxB = csr[start + j0 + 4 + lk];
    int c8 = deg - j0;
    int ss[8];
#pragma unroll
    for (int jj = 0; jj < 4; jj++) ss[jj] = __shfl(idxA, lm + jj * 16);
#pragma unroll
    for (int jj = 0; jj < 4; jj++) ss[4 + jj] = __shfl(idxB, lm + jj * 16);
    uint4 va[8], vb[8];
#pragma unroll
    for (int jj = 0; jj < 8; jj++) {
      const unsigned short* rp = rhin + (size_t)ss[jj] * 64 + lk * 8;
      va[jj] = *(const uint4*)rp;
      vb[jj] = *(const uint4*)(rp + 32);
    }
#pragma unroll
    for (int jj = 0; jj < 8; jj++) {
      if (jj < c8) {
        uint4 vA = va[jj], vB = vb[jj];
        accA[0] += __uint_as_float(vA.x << 16);
        accA[1] += __uint_as_float(vA.x & 0xFFFF0000u);
        accA[2] += __uint_as_float(vA.y << 16);
        accA[3] += __uint_as_float(vA.y & 0xFFFF0000u);
        accA[4] += __uint_as_float(vA.z << 16);
        accA[5] += __uint_as_float(vA.z & 0xFFFF0000u);
        accA[6] += __uint_as_float(vA.w << 16);
        accA[7] += __uint_as_float(vA.w & 0xFFFF0000u);
        accB[0] += __uint_as_float(vB.x << 16);
        accB[1] += __uint_as_float(vB.x & 0xFFFF0000u);
        accB[2] += __uint_as_float(vB.y << 16);
        accB[3] += __uint_as_float(vB.y & 0xFFFF0000u);
        accB[4] += __uint_as_float(vB.z << 16);
        accB[5] += __uint_as_float(vB.z & 0xFFFF0000u);
        accB[6] += __uint_as_float(vB.w << 16);
        accB[7] += __uint_as_float(vB.w & 0xFFFF0000u);
      }
    }
  }

  // z = (1+eps)*h + agg -> A-frags
  bf16x8 a1[2];
  {
    const float* h0p = &hv0.x;
    const float* h1p = &hv2.x;
#pragma unroll
    for (int j = 0; j < 4; j++) {
      a1[0][j] = (short)bf16bits(epsv * h0p[j] + accA[j]);
      a1[0][4 + j] = (short)bf16bits(epsv * (&hv1.x)[j] + accA[4 + j]);
      a1[1][j] = (short)bf16bits(epsv * h1p[j] + accB[j]);
      a1[1][4 + j] = (short)bf16bits(epsv * (&hv3.x)[j] + accB[4 + j]);
    }
  }
  __syncthreads();

  // GEMM1: acc1[n] over 8 col-tiles (sW holds W1)
  f32x4 acc1[8];
#pragma unroll
  for (int n = 0; n < 8; n++) {
    float bc = sb1[n * 16 + lm];
    acc1[n] = (f32x4){bc, bc, bc, bc};
  }
  {
    const bf16x8* sW1f = (const bf16x8*)sW;
#pragma unroll
    for (int n = 0; n < 8; n++) {
      int c = n * 16 + lm;
      bf16x8 b0 = sW1f[c * 8 + ((0 * 4 + lk) ^ (c & 7))];
      bf16x8 b1f = sW1f[c * 8 + ((1 * 4 + lk) ^ (c & 7))];
      acc1[n] = __builtin_amdgcn_mfma_f32_16x16x32_bf16(a1[0], b0, acc1[n], 0, 0, 0);
      acc1[n] = __builtin_amdgcn_mfma_f32_16x16x32_bf16(a1[1], b1f, acc1[n], 0, 0, 0);
    }
  }

  // LayerNorm + relu on D-frags, write swizzled sRr
  float psr[4], pqr[4];
#pragma unroll
  for (int r = 0; r < 4; r++) {
    float s = 0.f, q = 0.f;
#pragma unroll
    for (int n = 0; n < 8; n++) { float v = acc1[n][r]; s += v; q += v * v; }
    psr[r] = s; pqr[r] = q;
  }
#pragma unroll
  for (int m = 1; m <= 8; m <<= 1) {
#pragma unroll
    for (int r = 0; r < 4; r++) {
      psr[r] += __shfl_xor(psr[r], m);
      pqr[r] += __shfl_xor(pqr[r], m);
    }
  }
#pragma unroll
  for (int r = 0; r < 4; r++) {
    float mu = psr[r] * (1.0f / 128.0f);
    float var = pqr[r] * (1.0f / 128.0f) - mu * mu;
    float rs = rsqrtf(var + 1e-5f);
    int rowr = w * 16 + lk * 4 + r;
#pragma unroll
    for (int n = 0; n < 8; n++) {
      int c = n * 16 + lm;
      float v = (acc1[n][r] - mu) * rs * sg[c] + sbt[c];
      v = fmaxf(v, 0.f);
      int slot = (c >> 3) ^ (rowr & 7);
      sRr[rowr * 128 + slot * 8 + (c & 7)] = bf16bits(v);
    }
  }
  __syncthreads();   // sRr ready; all waves past GEMM1 -> sW reusable

  // restage sW = W2 (L2-resident; swizzled 16B slots)
  {
    const uint4* w2g = (const uint4*)W2t;
    uint4* sWu = (uint4*)sW;
    for (int g = t; g < 1024; g += 256) {
      int c = g >> 4, s = g & 15;
      sWu[c * 16 + (s ^ (c & 15))] = w2g[g];
    }
  }
  __syncthreads();   // sW2 ready

  // GEMM2
  f32x4 acc2[4];
#pragma unroll
  for (int n2 = 0; n2 < 4; n2++) {
    float bc = sb2[n2 * 16 + lm];
    acc2[n2] = (f32x4){bc, bc, bc, bc};
  }
  {
    const bf16x8* sRf = (const bf16x8*)sRr;
    const bf16x8* sW2f = (const bf16x8*)sW;
    bf16x8 a2[4];
#pragma unroll
    for (int kb = 0; kb < 4; kb++)
      a2[kb] = sRf[rowl * 16 + ((kb * 4 + lk) ^ (rowl & 7))];
#pragma unroll
    for (int n2 = 0; n2 < 4; n2++) {
      int c = n2 * 16 + lm;
#pragma unroll
      for (int kb = 0; kb < 4; kb++) {
        bf16x8 bfr = sW2f[c * 16 + ((kb * 4 + lk) ^ (c & 15))];
        acc2[n2] = __builtin_amdgcn_mfma_f32_16x16x32_bf16(a2[kb], bfr, acc2[n2], 0, 0, 0);
      }
    }
  }

  // epilogue: h += out + b2 ; rhout = bf16(relu(h))
#pragma unroll
  for (int r = 0; r < 4; r++) {
    int grow2 = nbase + w * 16 + lk * 4 + r;
    if (grow2 < NN) {
#pragma unroll
      for (int n2 = 0; n2 < 4; n2++) {
        int c = n2 * 16 + lm;
        size_t idx = (size_t)grow2 * 64 + c;
        float o = h[idx] + acc2[n2][r];
        h[idx] = o;
        rhout[idx] = bf16bits(fmaxf(o, 0.f));
      }
    }
  }
}

// ---------------- pooling ----------------
__global__ void k_pool(const float* __restrict__ h, const int* __restrict__ batch,
                       float* __restrict__ pooled, int n) {
  int t = threadIdx.x;
  int d = t & 63;
  int w = t >> 6;
  int n0 = blockIdx.x * 256 + w * 64;
  float acc = 0.f;
  int prev = -1;
  for (int i = 0; i < 64; i++) {
    int nn = n0 + i;
    if (nn >= n) break;
    int g = batch[nn];
    if (g != prev) {
      if (prev >= 0) atomicAdd(&pooled[prev * 64 + d], acc);
      prev = g;
      acc = 0.f;
    }
    acc += h[(size_t)nn * 64 + d];
  }
  if (prev >= 0) atomicAdd(&pooled[prev * 64 + d], acc);
}

// ---------------- output MLP: one block per graph ----------------
// 128 threads; thread c computes t1[c] = bo1[c] + pooled[g,:]@Wo1[:,c];
// then 2-wave reduce of relu(t1)*Wo2[c].
__global__ __launch_bounds__(128) void k_out(
    const float* __restrict__ pooled, const float* __restrict__ Wo1,
    const float* __restrict__ bo1, const float* __restrict__ Wo2,
    const float* __restrict__ bo2, float* __restrict__ out) {
  __shared__ __align__(16) float sP[64];
  __shared__ float sPart[2];
  int g = blockIdx.x;
  int c = threadIdx.x;
  if (c < 64) sP[c] = pooled[g * 64 + c];
  __syncthreads();
  float t1 = bo1[c];
#pragma unroll 8
  for (int k = 0; k < 64; k++) t1 += sP[k] * Wo1[k * 128 + c];
  float v = fmaxf(t1, 0.f) * Wo2[c];
#pragma unroll
  for (int m = 1; m <= 32; m <<= 1) v += __shfl_xor(v, m);
  if ((c & 63) == 0) sPart[c >> 6] = v;
  __syncthreads();
  if (c == 0) out[g] = sPart[0] + sPart[1] + bo2[0];
}

// ---------------- launch ----------------

static inline char* align_up(char* p, size_t a) {
  return (char*)(((uintptr_t)p + a - 1) & ~(uintptr_t)(a - 1));
}

extern "C" void kernel_launch(void* const* d_in, const int* in_sizes, int n_in,
                              void* d_out, int out_size, void* d_ws, size_t ws_size,
                              hipStream_t stream) {
  const float* x    = (const float*)d_in[0];
  const float* W_in = (const float*)d_in[1];
  const float* b_in = (const float*)d_in[2];
  const float* eps  = (const float*)d_in[3];
  const float* W1   = (const float*)d_in[4];
  const float* b1   = (const float*)d_in[5];
  const float* gam  = (const float*)d_in[6];
  const float* bet  = (const float*)d_in[7];
  const float* W2   = (const float*)d_in[8];
  const float* b2   = (const float*)d_in[9];
  const float* Wo1  = (const float*)d_in[10];
  const float* bo1  = (const float*)d_in[11];
  const float* Wo2  = (const float*)d_in[12];
  const float* bo2  = (const float*)d_in[13];
  const int* ei     = (const int*)d_in[14];
  const int* batch  = (const int*)d_in[15];
  float* out = (float*)d_out;

  const int* e_src = ei;
  const int* e_dst = ei + NE;

  char* p = (char*)d_ws;
  float* h = (float*)p;                     p += (size_t)NN * 64 * 4;   // 25.6 MB
  unsigned short* rh0 = (unsigned short*)p; p += (size_t)NN * 64 * 2;   // 12.8 MB
  unsigned short* rh1 = (unsigned short*)p;
  unsigned int* tmp = (unsigned int*)p;     // tmp aliases rh1 (dead before layer 0)
                                            p += (size_t)NN * 64 * 2;   // 12.8 MB
  int* csr = (int*)p;
  int* hist = (int*)p;                      // hist aliases csr (dead before fillB2)
                                            p += (size_t)NE * 4;        // 6.4 MB
  int* offs = (int*)p;                      p += (size_t)NN * 4;
  int* cnt = (int*)p;                       p += (size_t)NN * 4;
  int* bsumH = (int*)p;                     p += 1280 * 4;
  int* bbase = (int*)p;                     p += (NBUCKET + 1) * 4;
  p = align_up(p, 256);
  float* pooled = (float*)p;                p += (size_t)NGRAPH * 64 * 4;
  p = align_up(p, 256);
  unsigned short* W1t = (unsigned short*)p; p += (size_t)NLAYERS * 8192 * 2;
  unsigned short* W2t = (unsigned short*)p; p += (size_t)NLAYERS * 8192 * 2;
  unsigned short* Wint = (unsigned short*)p; p += 4096 * 2;

  const int SCAN_BLOCKS_H = (NTOT + 255) / 256;      // 1195
  const int NODE_BLOCKS = (NN + 63) / 64;            // 1563

  hipMemsetAsync(pooled, 0, (size_t)NGRAPH * 64 * 4, stream);

  k_hist<<<NCHUNK, 256, 0, stream>>>(e_dst, hist);
  k_scan1<<<SCAN_BLOCKS_H, 256, 0, stream>>>(hist, hist, bsumH, NTOT);
  k_scan2b<<<1, 256, 0, stream>>>(bsumH, SCAN_BLOCKS_H);
  k_scan3b<<<SCAN_BLOCKS_H, 256, 0, stream>>>(hist, bsumH, bbase, NTOT);
  k_scatter<<<NCHUNK, 256, 0, stream>>>(e_src, e_dst, hist, tmp);
  k_fillB2<<<NBUCKET, 256, 0, stream>>>(tmp, bbase, csr, offs, cnt);

  k_prep<<<NLAYERS * 2 + 1, 256, 0, stream>>>(W1, W2, W_in, W1t, W2t, Wint);
  k_lin<<<NODE_BLOCKS, 256, 0, stream>>>(x, Wint, b_in, h, rh0);

  for (int l = 0; l < NLAYERS; l++) {
    unsigned short* rin  = (l & 1) ? rh1 : rh0;
    unsigned short* rout = (l & 1) ? rh0 : rh1;
    k_fused<<<NODE_BLOCKS, 256, 0, stream>>>(h, rin, rout, csr, offs, cnt,
        W1t + (size_t)l * 8192, b1 + (size_t)l * 128,
        gam + (size_t)l * 128, bet + (size_t)l * 128,
        W2t + (size_t)l * 8192, b2 + (size_t)l * 64,
        eps + l);
  }

  k_pool<<<(NN + 255) / 256, 256, 0, stream>>>(h, batch, pooled, NN);
  k_out<<<NGRAPH, 128, 0, stream>>>(pooled, Wo1, bo1, Wo2, bo2, out);
}

// Round 8
// 339.613 us; speedup vs baseline: 3.2821x; 1.0231x over previous
//
#include <hip/hip_runtime.h>
#include <hip/hip_bf16.h>

#define NN 100000
#define NE 1600000
#define DD 64
#define HH 128
#define NLAYERS 4
#define NGRAPH 64
#define NBUCKET 782        // ceil(NN/128) buckets of 128 dst nodes
#define NCHUNK 391         // ceil(NE/4096) edge chunks of 4096
#define NTOT (NBUCKET * NCHUNK)

typedef __attribute__((ext_vector_type(8))) short bf16x8;
typedef __attribute__((ext_vector_type(4))) float f32x4;

__device__ inline unsigned short bf16bits(float v) {
  return __bfloat16_as_ushort(__float2bfloat16(v));
}
__device__ inline float lo16(unsigned int u) { return __uint_as_float(u << 16); }
__device__ inline float hi16(unsigned int u) { return __uint_as_float(u & 0xFFFF0000u); }
__device__ inline float b2f(unsigned short u) { return __uint_as_float(((unsigned int)u) << 16); }

// ---------------- CSR build ----------------

__global__ void k_hist(const int* __restrict__ dst, int* __restrict__ hist) {
  __shared__ int lh[NBUCKET];
  int t = threadIdx.x;
  int blk = blockIdx.x;
  for (int i = t; i < NBUCKET; i += 256) lh[i] = 0;
  __syncthreads();
  int cb = blk * 4096;
  int end = min(cb + 4096, NE);
  for (int i = cb + t; i < end; i += 256)
    atomicAdd(&lh[dst[i] >> 7], 1);
  __syncthreads();
  for (int i = t; i < NBUCKET; i += 256)
    hist[i * NCHUNK + blk] = lh[i];
}

__global__ void k_scan1(const int* __restrict__ in, int* __restrict__ out,
                        int* __restrict__ bsum, int n) {
  __shared__ int s[256];
  int t = threadIdx.x;
  int i = blockIdx.x * 256 + t;
  int v = (i < n) ? in[i] : 0;
  s[t] = v;
  __syncthreads();
  for (int off = 1; off < 256; off <<= 1) {
    int x = (t >= off) ? s[t - off] : 0;
    __syncthreads();
    s[t] += x;
    __syncthreads();
  }
  if (i < n) out[i] = s[t] - v;
  if (t == 255) bsum[blockIdx.x] = s[255];
}

__global__ void k_scan2b(int* bsum, int nb) {
  __shared__ int s[256];
  int t = threadIdx.x;
  int base = t * 5;
  int v[5];
  int sum = 0;
#pragma unroll
  for (int j = 0; j < 5; j++) {
    int i = base + j;
    v[j] = (i < nb) ? bsum[i] : 0;
    sum += v[j];
  }
  s[t] = sum;
  __syncthreads();
  for (int off = 1; off < 256; off <<= 1) {
    int x = (t >= off) ? s[t - off] : 0;
    __syncthreads();
    s[t] += x;
    __syncthreads();
  }
  int ex = s[t] - sum;
#pragma unroll
  for (int j = 0; j < 5; j++) {
    int i = base + j;
    if (i < nb) { int vv = v[j]; bsum[i] = ex; ex += vv; }
  }
}

// finalize hist offsets + extract per-bucket bases (avoids hist/csr alias race)
__global__ void k_scan3b(int* __restrict__ hist, const int* __restrict__ bsum,
                         int* __restrict__ bbase, int n) {
  int i = blockIdx.x * 256 + threadIdx.x;
  if (i < n) {
    int v = hist[i] + bsum[i >> 8];
    hist[i] = v;
    if (i % NCHUNK == 0) bbase[i / NCHUNK] = v;
  }
}

__global__ void k_scatter(const int* __restrict__ src, const int* __restrict__ dst,
                          const int* __restrict__ hist, unsigned int* __restrict__ tmp) {
  __shared__ int lcur[NBUCKET];
  int t = threadIdx.x;
  int blk = blockIdx.x;
  for (int i = t; i < NBUCKET; i += 256) lcur[i] = hist[i * NCHUNK + blk];
  __syncthreads();
  int cb = blk * 4096;
  int end = min(cb + 4096, NE);
  for (int i = cb + t; i < end; i += 256) {
    int d = dst[i];
    int pos = atomicAdd(&lcur[d >> 7], 1);
    tmp[pos] = ((unsigned int)(d & 127) << 20) | (unsigned int)src[i];
  }
}

// per-bucket: derive per-node offs/cnt (LDS count+scan), then place edges
__global__ void k_fillB2(const unsigned int* __restrict__ tmp,
                         const int* __restrict__ bbase,
                         int* __restrict__ csr, int* __restrict__ offs,
                         int* __restrict__ cnt) {
  __shared__ int lcnt[128], lex[128], lcur[128];
  int b = blockIdx.x;
  int t = threadIdx.x;
  int base = bbase[b];
  int end = (b == NBUCKET - 1) ? NE : bbase[b + 1];
  if (t < 128) lcnt[t] = 0;
  __syncthreads();
  for (int i = base + t; i < end; i += 256)
    atomicAdd(&lcnt[tmp[i] >> 20], 1);
  __syncthreads();
  int v = (t < 128) ? lcnt[t] : 0;
  if (t < 128) lex[t] = v;
  __syncthreads();
  for (int off = 1; off < 128; off <<= 1) {
    int x = (t >= off && t < 128) ? lex[t - off] : 0;
    __syncthreads();
    if (t < 128) lex[t] += x;
    __syncthreads();
  }
  if (t < 128) {
    int ex = lex[t] - v;
    lcur[t] = ex;
    int node = (b << 7) + t;
    if (node < NN) { offs[node] = base + ex; cnt[node] = v; }
  }
  __syncthreads();
  for (int i = base + t; i < end; i += 256) {
    unsigned int u = tmp[i];
    int dl = u >> 20;
    int pos = atomicAdd(&lcur[dl], 1);
    csr[base + pos] = u & 0xFFFFF;
  }
}

// ---------------- weight prep: bf16 transposed copies ----------------
__global__ void k_prep(const float* __restrict__ W1, const float* __restrict__ W2,
                       const float* __restrict__ W_in,
                       unsigned short* __restrict__ W1t, unsigned short* __restrict__ W2t,
                       unsigned short* __restrict__ Wint) {
  int bidx = blockIdx.x;
  int t = threadIdx.x;
  if (bidx == 2 * NLAYERS) {
    for (int i = t; i < 4096; i += 256) {
      int c = i >> 6, k = i & 63;
      Wint[i] = bf16bits(W_in[k * 64 + c]);
    }
    return;
  }
  int l = bidx >> 1;
  int m = bidx & 1;
  if (m == 0) {
    const float* src = W1 + (size_t)l * 8192;
    unsigned short* dstp = W1t + (size_t)l * 8192;
    for (int i = t; i < 8192; i += 256) {
      int c = i >> 6, k = i & 63;
      dstp[i] = bf16bits(src[k * 128 + c]);
    }
  } else {
    const float* src = W2 + (size_t)l * 8192;
    unsigned short* dstp = W2t + (size_t)l * 8192;
    for (int i = t; i < 8192; i += 256) {
      int c = i >> 7, k = i & 127;
      dstp[i] = bf16bits(src[k * 64 + c]);
    }
  }
}

// ---------------- lin_in via MFMA: h = bf16(x @ W_in + b_in) ----------------
__global__ __launch_bounds__(256) void k_lin(
    const float* __restrict__ x, const unsigned short* __restrict__ Wint,
    const float* __restrict__ binp, unsigned short* __restrict__ hout) {
  __shared__ __align__(16) unsigned short sW[4096];   // [c=64][8 slots swz]
  __shared__ float sb[64];
  int t = threadIdx.x;
  {
    const uint4* wg = (const uint4*)Wint;
    uint4* sWu = (uint4*)sW;
    for (int g = t; g < 512; g += 256) {
      int c = g >> 3, s = g & 7;
      sWu[c * 8 + (s ^ (c & 7))] = wg[g];
    }
    if (t < 64) sb[t] = binp[t];
  }
  int l = t & 63, w = t >> 6, lm = l & 15, lk = l >> 4;
  int rowl = w * 16 + lm;
  int grow = blockIdx.x * 64 + rowl;
  int growc = min(grow, NN - 1);
  bf16x8 a[2];
#pragma unroll
  for (int kb = 0; kb < 2; kb++) {
    const float* xp = &x[(size_t)growc * 64 + kb * 32 + lk * 8];
    float4 x0 = *(const float4*)xp;
    float4 x1 = *(const float4*)(xp + 4);
    a[kb][0] = (short)bf16bits(x0.x); a[kb][1] = (short)bf16bits(x0.y);
    a[kb][2] = (short)bf16bits(x0.z); a[kb][3] = (short)bf16bits(x0.w);
    a[kb][4] = (short)bf16bits(x1.x); a[kb][5] = (short)bf16bits(x1.y);
    a[kb][6] = (short)bf16bits(x1.z); a[kb][7] = (short)bf16bits(x1.w);
  }
  __syncthreads();
  f32x4 acc[4];
#pragma unroll
  for (int n = 0; n < 4; n++) {
    float bc = sb[n * 16 + lm];
    acc[n] = (f32x4){bc, bc, bc, bc};
  }
  const bf16x8* sWf = (const bf16x8*)sW;
#pragma unroll
  for (int n = 0; n < 4; n++) {
    int c = n * 16 + lm;
    bf16x8 b0 = sWf[c * 8 + ((0 * 4 + lk) ^ (c & 7))];
    bf16x8 b1 = sWf[c * 8 + ((1 * 4 + lk) ^ (c & 7))];
    acc[n] = __builtin_amdgcn_mfma_f32_16x16x32_bf16(a[0], b0, acc[n], 0, 0, 0);
    acc[n] = __builtin_amdgcn_mfma_f32_16x16x32_bf16(a[1], b1, acc[n], 0, 0, 0);
  }
#pragma unroll
  for (int r = 0; r < 4; r++) {
    int grow2 = blockIdx.x * 64 + w * 16 + lk * 4 + r;
    if (grow2 < NN) {
#pragma unroll
      for (int n = 0; n < 4; n++) {
        int c = n * 16 + lm;
        hout[(size_t)grow2 * 64 + c] = bf16bits(acc[n][r]);
      }
    }
  }
}

// ---------------- fused layer: gather + MLP (MFMA), all-bf16 h ----------------
// 64 nodes/block, 4 waves. Gather relu(hin[src]) 8-edge-batched (clamped);
// z = (1+eps)*hin + agg -> A-frags; GEMM1 (sW=W1); LN+relu -> sRr;
// restage sW=W2; GEMM2; hout = hin + out. LDS ~33.8 KB -> 4 blocks/CU.
__global__ __launch_bounds__(256) void k_fused(
    const unsigned short* __restrict__ hin, unsigned short* __restrict__ hout,
    const int* __restrict__ csr, const int* __restrict__ offs,
    const int* __restrict__ cnt,
    const unsigned short* __restrict__ W1t, const float* __restrict__ b1l,
    const float* __restrict__ gl, const float* __restrict__ btl,
    const unsigned short* __restrict__ W2t, const float* __restrict__ b2l,
    const float* __restrict__ epsl) {
  __shared__ __align__(16) unsigned short sW[8192];   // W1 [c=128][8 swz] then W2 [c=64][16 swz]
  __shared__ __align__(16) unsigned short sRr[8192];  // [r=64][16 slots swz]
  __shared__ float sb1[128], sg[128], sbt[128], sb2[64];

  int t = threadIdx.x;
  int nbase = blockIdx.x * 64;
  int l = t & 63;
  int w = t >> 6;
  int lm = l & 15;
  int lk = l >> 4;

  // stage W1 (swizzled 16B slots) + params
  {
    const uint4* w1g = (const uint4*)W1t;
    uint4* sWu = (uint4*)sW;
    for (int g = t; g < 1024; g += 256) {
      int c = g >> 3, s = g & 7;
      sWu[c * 8 + (s ^ (c & 7))] = w1g[g];
    }
    if (t < 128) { sb1[t] = b1l[t]; sg[t] = gl[t]; sbt[t] = btl[t]; }
    if (t < 64) sb2[t] = b2l[t];
  }
  float epsv = 1.0f + *epsl;

  int rowl = w * 16 + lm;
  int grow = nbase + rowl;
  int growc = min(grow, NN - 1);
  int start = offs[growc];
  int deg = (grow < NN) ? cnt[growc] : 0;

  // issue-early: own-row h (bf16), consumed after the gather loop
  const unsigned short* hp = hin + (size_t)growc * 64 + lk * 8;
  uint4 hva = *(const uint4*)hp;
  uint4 hvb = *(const uint4*)(hp + 32);

  // ---- gather: 4 threads/node, 16 dims each; 8 edges batched, clamped ----
  float accA[8] = {0.f, 0.f, 0.f, 0.f, 0.f, 0.f, 0.f, 0.f};
  float accB[8] = {0.f, 0.f, 0.f, 0.f, 0.f, 0.f, 0.f, 0.f};
  for (int j0 = 0; j0 < deg; j0 += 8) {
    int idxA = csr[start + j0 + lk];          // over-read <= +7 ints, clamped below
    int idxB = csr[start + j0 + 4 + lk];
    int c8 = deg - j0;
    int ss[8];
#pragma unroll
    for (int jj = 0; jj < 4; jj++) ss[jj] = __shfl(idxA, lm + jj * 16);
#pragma unroll
    for (int jj = 0; jj < 4; jj++) ss[4 + jj] = __shfl(idxB, lm + jj * 16);
    uint4 va[8], vb[8];
#pragma unroll
    for (int jj = 0; jj < 8; jj++) {
      int s = (jj < c8) ? ss[jj] : ss[0];     // clamp: repeat addr = cache hit
      const unsigned short* rp = hin + (size_t)s * 64 + lk * 8;
      va[jj] = *(const uint4*)rp;
      vb[jj] = *(const uint4*)(rp + 32);
    }
#pragma unroll
    for (int jj = 0; jj < 8; jj++) {
      if (jj < c8) {
        uint4 vA = va[jj], vB = vb[jj];
        accA[0] += fmaxf(lo16(vA.x), 0.f);
        accA[1] += fmaxf(hi16(vA.x), 0.f);
        accA[2] += fmaxf(lo16(vA.y), 0.f);
        accA[3] += fmaxf(hi16(vA.y), 0.f);
        accA[4] += fmaxf(lo16(vA.z), 0.f);
        accA[5] += fmaxf(hi16(vA.z), 0.f);
        accA[6] += fmaxf(lo16(vA.w), 0.f);
        accA[7] += fmaxf(hi16(vA.w), 0.f);
        accB[0] += fmaxf(lo16(vB.x), 0.f);
        accB[1] += fmaxf(hi16(vB.x), 0.f);
        accB[2] += fmaxf(lo16(vB.y), 0.f);
        accB[3] += fmaxf(hi16(vB.y), 0.f);
        accB[4] += fmaxf(lo16(vB.z), 0.f);
        accB[5] += fmaxf(hi16(vB.z), 0.f);
        accB[6] += fmaxf(lo16(vB.w), 0.f);
        accB[7] += fmaxf(hi16(vB.w), 0.f);
      }
    }
  }

  // z = (1+eps)*h + agg -> A-frags
  bf16x8 a1[2];
  {
    float hz[8];
    hz[0] = lo16(hva.x); hz[1] = hi16(hva.x); hz[2] = lo16(hva.y); hz[3] = hi16(hva.y);
    hz[4] = lo16(hva.z); hz[5] = hi16(hva.z); hz[6] = lo16(hva.w); hz[7] = hi16(hva.w);
#pragma unroll
    for (int j = 0; j < 8; j++) a1[0][j] = (short)bf16bits(epsv * hz[j] + accA[j]);
    hz[0] = lo16(hvb.x); hz[1] = hi16(hvb.x); hz[2] = lo16(hvb.y); hz[3] = hi16(hvb.y);
    hz[4] = lo16(hvb.z); hz[5] = hi16(hvb.z); hz[6] = lo16(hvb.w); hz[7] = hi16(hvb.w);
#pragma unroll
    for (int j = 0; j < 8; j++) a1[1][j] = (short)bf16bits(epsv * hz[j] + accB[j]);
  }
  __syncthreads();

  // GEMM1: acc1[n] over 8 col-tiles (sW holds W1)
  f32x4 acc1[8];
#pragma unroll
  for (int n = 0; n < 8; n++) {
    float bc = sb1[n * 16 + lm];
    acc1[n] = (f32x4){bc, bc, bc, bc};
  }
  {
    const bf16x8* sW1f = (const bf16x8*)sW;
#pragma unroll
    for (int n = 0; n < 8; n++) {
      int c = n * 16 + lm;
      bf16x8 b0 = sW1f[c * 8 + ((0 * 4 + lk) ^ (c & 7))];
      bf16x8 b1f = sW1f[c * 8 + ((1 * 4 + lk) ^ (c & 7))];
      acc1[n] = __builtin_amdgcn_mfma_f32_16x16x32_bf16(a1[0], b0, acc1[n], 0, 0, 0);
      acc1[n] = __builtin_amdgcn_mfma_f32_16x16x32_bf16(a1[1], b1f, acc1[n], 0, 0, 0);
    }
  }

  // LayerNorm + relu on D-frags, write swizzled sRr
  float psr[4], pqr[4];
#pragma unroll
  for (int r = 0; r < 4; r++) {
    float s = 0.f, q = 0.f;
#pragma unroll
    for (int n = 0; n < 8; n++) { float v = acc1[n][r]; s += v; q += v * v; }
    psr[r] = s; pqr[r] = q;
  }
#pragma unroll
  for (int m = 1; m <= 8; m <<= 1) {
#pragma unroll
    for (int r = 0; r < 4; r++) {
      psr[r] += __shfl_xor(psr[r], m);
      pqr[r] += __shfl_xor(pqr[r], m);
    }
  }
#pragma unroll
  for (int r = 0; r < 4; r++) {
    float mu = psr[r] * (1.0f / 128.0f);
    float var = pqr[r] * (1.0f / 128.0f) - mu * mu;
    float rs = rsqrtf(var + 1e-5f);
    int rowr = w * 16 + lk * 4 + r;
#pragma unroll
    for (int n = 0; n < 8; n++) {
      int c = n * 16 + lm;
      float v = (acc1[n][r] - mu) * rs * sg[c] + sbt[c];
      v = fmaxf(v, 0.f);
      int slot = (c >> 3) ^ (rowr & 7);
      sRr[rowr * 128 + slot * 8 + (c & 7)] = bf16bits(v);
    }
  }
  __syncthreads();   // sRr ready; all waves past GEMM1 -> sW reusable

  // restage sW = W2 (L2-resident; swizzled 16B slots)
  {
    const uint4* w2g = (const uint4*)W2t;
    uint4* sWu = (uint4*)sW;
    for (int g = t; g < 1024; g += 256) {
      int c = g >> 4, s = g & 15;
      sWu[c * 16 + (s ^ (c & 15))] = w2g[g];
    }
  }
  __syncthreads();   // sW2 ready

  // GEMM2
  f32x4 acc2[4];
#pragma unroll
  for (int n2 = 0; n2 < 4; n2++) {
    float bc = sb2[n2 * 16 + lm];
    acc2[n2] = (f32x4){bc, bc, bc, bc};
  }
  {
    const bf16x8* sRf = (const bf16x8*)sRr;
    const bf16x8* sW2f = (const bf16x8*)sW;
    bf16x8 a2[4];
#pragma unroll
    for (int kb = 0; kb < 4; kb++)
      a2[kb] = sRf[rowl * 16 + ((kb * 4 + lk) ^ (rowl & 7))];
#pragma unroll
    for (int n2 = 0; n2 < 4; n2++) {
      int c = n2 * 16 + lm;
#pragma unroll
      for (int kb = 0; kb < 4; kb++) {
        bf16x8 bfr = sW2f[c * 16 + ((kb * 4 + lk) ^ (c & 15))];
        acc2[n2] = __builtin_amdgcn_mfma_f32_16x16x32_bf16(a2[kb], bfr, acc2[n2], 0, 0, 0);
      }
    }
  }

  // epilogue: hout = hin + out + b2   (bf16 residual)
#pragma unroll
  for (int r = 0; r < 4; r++) {
    int grow2 = nbase + w * 16 + lk * 4 + r;
    if (grow2 < NN) {
#pragma unroll
      for (int n2 = 0; n2 < 4; n2++) {
        int c = n2 * 16 + lm;
        size_t idx = (size_t)grow2 * 64 + c;
        float o = b2f(hin[idx]) + acc2[n2][r];
        hout[idx] = bf16bits(o);
      }
    }
  }
}

// ---------------- pooling (bf16 h) ----------------
__global__ void k_pool(const unsigned short* __restrict__ h,
                       const int* __restrict__ batch,
                       float* __restrict__ pooled, int n) {
  int t = threadIdx.x;
  int d = t & 63;
  int w = t >> 6;
  int n0 = blockIdx.x * 256 + w * 64;
  float acc = 0.f;
  int prev = -1;
  for (int i = 0; i < 64; i++) {
    int nn = n0 + i;
    if (nn >= n) break;
    int g = batch[nn];
    if (g != prev) {
      if (prev >= 0) atomicAdd(&pooled[prev * 64 + d], acc);
      prev = g;
      acc = 0.f;
    }
    acc += b2f(h[(size_t)nn * 64 + d]);
  }
  if (prev >= 0) atomicAdd(&pooled[prev * 64 + d], acc);
}

// ---------------- output MLP: one block per graph ----------------
__global__ __launch_bounds__(128) void k_out(
    const float* __restrict__ pooled, const float* __restrict__ Wo1,
    const float* __restrict__ bo1, const float* __restrict__ Wo2,
    const float* __restrict__ bo2, float* __restrict__ out) {
  __shared__ __align__(16) float sP[64];
  __shared__ float sPart[2];
  int g = blockIdx.x;
  int c = threadIdx.x;
  if (c < 64) sP[c] = pooled[g * 64 + c];
  __syncthreads();
  float t1 = bo1[c];
#pragma unroll 8
  for (int k = 0; k < 64; k++) t1 += sP[k] * Wo1[k * 128 + c];
  float v = fmaxf(t1, 0.f) * Wo2[c];
#pragma unroll
  for (int m = 1; m <= 32; m <<= 1) v += __shfl_xor(v, m);
  if ((c & 63) == 0) sPart[c >> 6] = v;
  __syncthreads();
  if (c == 0) out[g] = sPart[0] + sPart[1] + bo2[0];
}

// ---------------- launch ----------------

static inline char* align_up(char* p, size_t a) {
  return (char*)(((uintptr_t)p + a - 1) & ~(uintptr_t)(a - 1));
}

extern "C" void kernel_launch(void* const* d_in, const int* in_sizes, int n_in,
                              void* d_out, int out_size, void* d_ws, size_t ws_size,
                              hipStream_t stream) {
  const float* x    = (const float*)d_in[0];
  const float* W_in = (const float*)d_in[1];
  const float* b_in = (const float*)d_in[2];
  const float* eps  = (const float*)d_in[3];
  const float* W1   = (const float*)d_in[4];
  const float* b1   = (const float*)d_in[5];
  const float* gam  = (const float*)d_in[6];
  const float* bet  = (const float*)d_in[7];
  const float* W2   = (const float*)d_in[8];
  const float* b2   = (const float*)d_in[9];
  const float* Wo1  = (const float*)d_in[10];
  const float* bo1  = (const float*)d_in[11];
  const float* Wo2  = (const float*)d_in[12];
  const float* bo2  = (const float*)d_in[13];
  const int* ei     = (const int*)d_in[14];
  const int* batch  = (const int*)d_in[15];
  float* out = (float*)d_out;

  const int* e_src = ei;
  const int* e_dst = ei + NE;

  char* p = (char*)d_ws;
  unsigned short* hA = (unsigned short*)p;  p += (size_t)NN * 64 * 2;   // 12.8 MB
  unsigned short* hB = (unsigned short*)p;
  unsigned int* tmp = (unsigned int*)p;     // tmp aliases hB (dead before layer 0)
                                            p += (size_t)NN * 64 * 2;   // 12.8 MB
  int* csr = (int*)p;
  int* hist = (int*)p;                      // hist aliases csr (dead before fillB2)
                                            p += (size_t)NE * 4;        // 6.4 MB
  int* offs = (int*)p;                      p += (size_t)NN * 4;
  int* cnt = (int*)p;                       p += (size_t)NN * 4;
  int* bsumH = (int*)p;                     p += 1280 * 4;
  int* bbase = (int*)p;                     p += (NBUCKET + 1) * 4;
  p = align_up(p, 256);
  float* pooled = (float*)p;                p += (size_t)NGRAPH * 64 * 4;
  p = align_up(p, 256);
  unsigned short* W1t = (unsigned short*)p; p += (size_t)NLAYERS * 8192 * 2;
  unsigned short* W2t = (unsigned short*)p; p += (size_t)NLAYERS * 8192 * 2;
  unsigned short* Wint = (unsigned short*)p; p += 4096 * 2;

  const int SCAN_BLOCKS_H = (NTOT + 255) / 256;      // 1195
  const int NODE_BLOCKS = (NN + 63) / 64;            // 1563

  hipMemsetAsync(pooled, 0, (size_t)NGRAPH * 64 * 4, stream);

  k_hist<<<NCHUNK, 256, 0, stream>>>(e_dst, hist);
  k_scan1<<<SCAN_BLOCKS_H, 256, 0, stream>>>(hist, hist, bsumH, NTOT);
  k_scan2b<<<1, 256, 0, stream>>>(bsumH, SCAN_BLOCKS_H);
  k_scan3b<<<SCAN_BLOCKS_H, 256, 0, stream>>>(hist, bsumH, bbase, NTOT);
  k_scatter<<<NCHUNK, 256, 0, stream>>>(e_src, e_dst, hist, tmp);
  k_fillB2<<<NBUCKET, 256, 0, stream>>>(tmp, bbase, csr, offs, cnt);

  k_prep<<<NLAYERS * 2 + 1, 256, 0, stream>>>(W1, W2, W_in, W1t, W2t, Wint);
  k_lin<<<NODE_BLOCKS, 256, 0, stream>>>(x, Wint, b_in, hA);

  for (int l = 0; l < NLAYERS; l++) {
    const unsigned short* hin = (l & 1) ? hB : hA;
    unsigned short* ho = (l & 1) ? hA : hB;
    k_fused<<<NODE_BLOCKS, 256, 0, stream>>>(hin, ho, csr, offs, cnt,
        W1t + (size_t)l * 8192, b1 + (size_t)l * 128,
        gam + (size_t)l * 128, bet + (size_t)l * 128,
        W2t + (size_t)l * 8192, b2 + (size_t)l * 64,
        eps + l);
  }

  k_pool<<<(NN + 255) / 256, 256, 0, stream>>>(hA, batch, pooled, NN);
  k_out<<<NGRAPH, 128, 0, stream>>>(pooled, Wo1, bo1, Wo2, bo2, out);
}